// Round 7
// baseline (335.722 us; speedup 1.0000x reference)
//
#include <hip/hip_runtime.h>
#include <stdint.h>

typedef unsigned short US;
typedef __attribute__((ext_vector_type(8))) short short8;
typedef __attribute__((ext_vector_type(8))) US us8;
typedef __attribute__((ext_vector_type(4))) float f32x4;
typedef __attribute__((ext_vector_type(4))) int i32x4;

#define DEV static __device__ __forceinline__

DEV US f2b(float f){
  uint32_t u = __builtin_bit_cast(uint32_t, f);
  return (US)((u + 0x7fffu + ((u >> 16) & 1u)) >> 16);
}
DEV float b2f(US s){
  return __builtin_bit_cast(float, (uint32_t)((uint32_t)s << 16));
}
DEV short8 ldsfrag(const US* p){
  return __builtin_bit_cast(short8, *(const i32x4*)p);
}
DEV f32x4 MFMA(short8 a, short8 b, f32x4 c){
  return __builtin_amdgcn_mfma_f32_16x16x32_bf16(a, b, c, 0, 0, 0);
}
DEV void async16(const US* g, US* l){
  __builtin_amdgcn_global_load_lds(
      (const __attribute__((address_space(1))) unsigned int*)(const void*)g,
      (__attribute__((address_space(3))) unsigned int*)(void*)l,
      16, 0, 0);
}

// ---------------- weight transpose + fp32->bf16 cast ----------------
struct WcvtArgs {
  const float* src[7];
  US* dst[7];
  int R[7];
  int C[7];
};

__global__ __launch_bounds__(256) void wcvt(WcvtArgs a){
  int z = blockIdx.z;
  int R = a.R[z], C = a.C[z];
  int tc = blockIdx.x*32, tr = blockIdx.y*32;
  if (tc >= C || tr >= R) return;
  __shared__ float T[32][33];
  int tx = threadIdx.x & 31, ty = threadIdx.x >> 5;
  const float* s = a.src[z];
  #pragma unroll
  for (int j=0;j<4;++j) T[ty + j*8][tx] = s[(size_t)(tr + ty + j*8)*C + tc + tx];
  __syncthreads();
  US* d = a.dst[z];
  #pragma unroll
  for (int j=0;j<4;++j) d[(size_t)(tc + ty + j*8)*R + tr + tx] = f2b(T[tx][ty + j*8]);
}

// ---------------- RMSNorm: fp32 row(512) -> bf16 ----------------
__global__ __launch_bounds__(256) void rmsnorm_k(const float* __restrict__ x,
                                                 const float* __restrict__ w,
                                                 US* __restrict__ o){
  int row = blockIdx.x*4 + (threadIdx.x >> 6);
  int l = threadIdx.x & 63;
  const float* xr = x + (size_t)row*512 + l*8;
  f32x4 a = *(const f32x4*)xr;
  f32x4 b = *(const f32x4*)(xr + 4);
  float ss = a[0]*a[0]+a[1]*a[1]+a[2]*a[2]+a[3]*a[3]
           + b[0]*b[0]+b[1]*b[1]+b[2]*b[2]+b[3]*b[3];
  #pragma unroll
  for (int mk=1; mk<64; mk<<=1) ss += __shfl_xor(ss, mk);
  float r = rsqrtf(ss*(1.0f/512.0f) + 1e-6f);
  const float* wr = w + l*8;
  f32x4 wa = *(const f32x4*)wr;
  f32x4 wb = *(const f32x4*)(wr + 4);
  us8 t;
  t[0]=f2b(a[0]*r*wa[0]); t[1]=f2b(a[1]*r*wa[1]);
  t[2]=f2b(a[2]*r*wa[2]); t[3]=f2b(a[3]*r*wa[3]);
  t[4]=f2b(b[0]*r*wb[0]); t[5]=f2b(b[1]*r*wb[1]);
  t[6]=f2b(b[2]*r*wb[2]); t[7]=f2b(b[3]*r*wb[3]);
  *(us8*)(o + (size_t)row*512 + l*8) = t;
}

// ---------------- GEMM 128x128 (BK=64, swizzled, 2-barrier) ----------------
// EPI: 1=out=auxf+acc   4=out+=acc
template<int EPI>
__global__ __launch_bounds__(256) void gemm_bt(
    const US* __restrict__ A, const US* __restrict__ BT,
    int M, int N, int K,
    void* __restrict__ outp, const float* __restrict__ auxf,
    US* __restrict__ auxb)
{
  __shared__ __attribute__((aligned(16))) US As[128*64];
  __shared__ __attribute__((aligned(16))) US Bs[128*64];
  const int tid = threadIdx.x, l = tid & 63, w = tid >> 6;
  const int wr = w >> 1, wc = w & 1;
  const int gx = gridDim.x;
  int wg = blockIdx.y*gx + blockIdx.x;
  const int nwg = gx * gridDim.y;
  const int qq = nwg >> 3;
  wg = (wg & 7)*qq + (wg >> 3);
  const int m0 = (wg / gx)*128, n0 = (wg % gx)*128;
  (void)M;
  f32x4 acc[4][4] = {};
  for (int k0 = 0; k0 < K; k0 += 64){
    #pragma unroll
    for (int p=0;p<4;++p){
      int off  = p*4096 + w*1024 + l*16;
      int row  = off >> 7;
      int slot = (off >> 4) & 7;
      int ce   = ((slot ^ (row & 7)) << 3);
      async16(A  + (size_t)(m0 + row)*K + k0 + ce, As + p*2048 + w*512);
      async16(BT + (size_t)(n0 + row)*K + k0 + ce, Bs + p*2048 + w*512);
    }
    __syncthreads();
    short8 af[2][4], bg[2][4];
    #pragma unroll
    for (int kk=0;kk<2;++kk){
      #pragma unroll
      for (int i=0;i<4;++i){
        int rowA = wr*64 + i*16 + (l&15);
        int sA = ((kk*4 + (l>>4)) ^ (rowA & 7)) << 3;
        af[kk][i] = ldsfrag(&As[rowA*64 + sA]);
        int rowB = wc*64 + i*16 + (l&15);
        int sB = ((kk*4 + (l>>4)) ^ (rowB & 7)) << 3;
        bg[kk][i] = ldsfrag(&Bs[rowB*64 + sB]);
      }
    }
    #pragma unroll
    for (int kk=0;kk<2;++kk)
      #pragma unroll
      for (int i=0;i<4;++i)
        #pragma unroll
        for (int j=0;j<4;++j)
          acc[i][j] = MFMA(af[kk][i], bg[kk][j], acc[i][j]);
    __syncthreads();
  }
  #pragma unroll
  for (int i=0;i<4;++i)
    #pragma unroll
    for (int j=0;j<4;++j)
      #pragma unroll
      for (int r=0;r<4;++r){
        int m  = m0 + wr*64 + i*16 + (l>>4)*4 + r;
        int nn = n0 + wc*64 + j*16 + (l&15);
        float val = acc[i][j][r];
        if constexpr (EPI == 1){
          float* o = (float*)outp;
          size_t idx = (size_t)m*N + nn;
          o[idx] = auxf[idx] + val;
        } else {
          float* o = (float*)outp;
          size_t idx = (size_t)m*N + nn;
          o[idx] += val;
        }
      }
  (void)auxb;
}

// ---------------- GEMM 256x256, 8 waves, dbuf LDS + counted vmcnt ----------------
// EPI: 0=QKV scatter bf16   2=bf16 raw   3=bf16 silu(auxb)*acc
template<int EPI>
__global__ __launch_bounds__(512, 2) void gemm256_bt(
    const US* __restrict__ A, const US* __restrict__ BT,
    int M, int N, int K,
    void* __restrict__ outp, US* __restrict__ auxb)
{
  __shared__ __attribute__((aligned(16))) US As[2][16384];
  __shared__ __attribute__((aligned(16))) US Bs[2][16384];
  const int tid = threadIdx.x, l = tid & 63, w = tid >> 6;
  const int wr = w >> 2, wc = w & 3;          // 2M x 4N waves
  const int gx = gridDim.x;
  int wg = blockIdx.y*gx + blockIdx.x;
  const int nwg = gx * gridDim.y;
  const int qq = nwg >> 3;
  wg = (wg & 7)*qq + (wg >> 3);
  const int m0 = (wg / gx)*256, n0 = (wg % gx)*256;
  (void)M;

  auto stage = [&](int buf, int kt){
    const int kb = kt*64;
    #pragma unroll
    for (int i=0;i<4;++i){
      int off  = i*8192 + tid*16;
      int row  = off >> 7;
      int slot = (off >> 4) & 7;
      int ce   = ((slot ^ (row & 7)) << 3);
      async16(A  + (size_t)(m0 + row)*K + kb + ce, &As[buf][i*4096 + tid*8]);
      async16(BT + (size_t)(n0 + row)*K + kb + ce, &Bs[buf][i*4096 + tid*8]);
    }
  };

  f32x4 acc[8][4] = {};
  const int nt = K >> 6;

  stage(0, 0);
  __builtin_amdgcn_sched_barrier(0);
  for (int t=0; t<nt; ++t){
    const int cur = t & 1;
    const bool hn = (t+1 < nt);
    if (hn) stage(cur^1, t+1);
    __builtin_amdgcn_sched_barrier(0);
    if (hn) asm volatile("s_waitcnt vmcnt(8)" ::: "memory");
    else    asm volatile("s_waitcnt vmcnt(0)" ::: "memory");
    __builtin_amdgcn_s_barrier();
    __builtin_amdgcn_sched_barrier(0);
    const US* Ac = As[cur];
    const US* Bc = Bs[cur];
    #pragma unroll
    for (int ks=0; ks<2; ++ks){
      short8 af[8], bg[4];
      #pragma unroll
      for (int m=0;m<8;++m){
        int row = wr*128 + m*16 + (l&15);
        int s = ((ks*4 + (l>>4)) ^ (row & 7)) << 3;
        af[m] = ldsfrag(&Ac[row*64 + s]);
      }
      #pragma unroll
      for (int n=0;n<4;++n){
        int row = wc*64 + n*16 + (l&15);
        int s = ((ks*4 + (l>>4)) ^ (row & 7)) << 3;
        bg[n] = ldsfrag(&Bc[row*64 + s]);
      }
      __builtin_amdgcn_s_setprio(1);
      #pragma unroll
      for (int m=0;m<8;++m)
        #pragma unroll
        for (int n=0;n<4;++n)
          acc[m][n] = MFMA(af[m], bg[n], acc[m][n]);
      __builtin_amdgcn_s_setprio(0);
    }
    __builtin_amdgcn_sched_barrier(0);
    __builtin_amdgcn_s_barrier();
    __builtin_amdgcn_sched_barrier(0);
  }

  #pragma unroll
  for (int m=0;m<8;++m)
    #pragma unroll
    for (int n=0;n<4;++n)
      #pragma unroll
      for (int r=0;r<4;++r){
        int mm = m0 + wr*128 + m*16 + (l>>4)*4 + r;
        int nn = n0 + wc*64 + n*16 + (l&15);
        float val = acc[m][n][r];
        if constexpr (EPI == 0){
          US* o = (US*)outp;
          int f = nn & 511, tq = nn >> 9;
          size_t idx = (size_t)tq*8388608
                     + ((size_t)(mm>>12)*8 + (size_t)(f>>6))*262144
                     + (size_t)(mm & 4095)*64 + (size_t)(f & 63);
          o[idx] = f2b(val);
        } else if constexpr (EPI == 2){
          US* o = (US*)outp;
          o[(size_t)mm*N + nn] = f2b(val);
        } else {
          US* o = (US*)outp;
          size_t idx = (size_t)mm*N + nn;
          float g = b2f(auxb[idx]);
          float sg = g / (1.f + __expf(-g));
          o[idx] = f2b(sg * val);
        }
      }
}

// ---------------- V transpose: [bh][4096][64] -> [bh][64][4096] ----------------
__global__ __launch_bounds__(256) void vtrans(const US* __restrict__ vin,
                                              US* __restrict__ vout){
  __shared__ US T[64*72];
  int s0 = blockIdx.x*64;
  int bh = blockIdx.y;
  int r = threadIdx.x >> 2, c0 = (threadIdx.x & 3)*16;
  const US* src = vin + ((size_t)bh*4096 + s0 + r)*64 + c0;
  *(i32x4*)&T[r*72 + c0]     = *(const i32x4*)src;
  *(i32x4*)&T[r*72 + c0 + 8] = *(const i32x4*)(src + 8);
  __syncthreads();
  int d = threadIdx.x >> 2, e0 = (threadIdx.x & 3)*16;
  US* dst = vout + ((size_t)bh*64 + d)*4096 + s0 + e0;
  us8 o0, o1;
  #pragma unroll
  for (int j=0;j<8;++j){ o0[j] = T[(e0+j)*72 + d]; o1[j] = T[(e0+8+j)*72 + d]; }
  *(us8*)dst = o0;
  *(us8*)(dst + 8) = o1;
}

// ---------------- pooling: K row-major + V^T, one level ----------------
__global__ __launch_bounds__(256) void poolkvt(
    const US* __restrict__ kin, US* __restrict__ kout,
    const US* __restrict__ vtin, US* __restrict__ vtout,
    int nin, int nout, int lgno, int noutS, int lgnoS)
{
  int t = blockIdx.x*256 + threadIdx.x;
  if (blockIdx.y == 0){
    if (t >= (nout << 11)) return;
    int d = t & 63;
    int c = (t >> 6) & (nout - 1);
    int bh = t >> (6 + lgno);
    const US* kp = kin + (((size_t)bh*nin) + (size_t)c*8)*64 + d;
    float s = 0.f;
    #pragma unroll
    for (int j=0;j<8;++j) s += b2f(kp[j*64]);
    kout[((size_t)bh*nout + c)*64 + d] = f2b(s*0.125f);
  } else {
    if (t >= (noutS << 11)) return;
    int c = t & (noutS - 1);
    int row = t >> lgnoS;
    US val = 0;
    if (c < nout){
      const US* vp = vtin + (size_t)row*nin + (size_t)c*8;
      us8 v = *(const us8*)vp;
      float s = 0.f;
      #pragma unroll
      for (int j=0;j<8;++j) s += b2f(v[j]);
      val = f2b(s*0.125f);
    }
    vtout[(size_t)row*noutS + c] = val;
  }
}

// ---------------- fused hierarchical attention (R2/R4-proven body) ----------------
template<int NFV, bool LOCAL>
DEV void flash_level(const US* __restrict__ kptr, const US* __restrict__ vtp,
                     int vstride, int ncK, int NCV,
                     int tile0, int ntiles, int lg,
                     int tid, int l, int w, int prow,
                     short8 aq0, short8 aq1,
                     US* Ks, US* Vs, US* Ps,
                     float* mrun, float* lsum, f32x4* olvl)
{
  for (int tt=0; tt<ntiles; ++tt){
    const int cb = (tile0 + tt)*128;
    __syncthreads();
    {
      int r = tid >> 2, c0 = (tid & 3)*16;
      if (cb + r < ncK){
        const US* kp = kptr + (size_t)(cb + r)*64 + c0;
        *(i32x4*)&Ks[r*72 + c0]     = *(const i32x4*)kp;
        *(i32x4*)&Ks[r*72 + c0 + 8] = *(const i32x4*)(kp + 8);
      }
      int d = tid >> 3, e0 = (tid & 7)*16;
      US* dst = &Vs[d*136 + e0];
      if (cb + e0 + 16 <= NCV){
        const US* vp = vtp + (size_t)d*vstride + cb + e0;
        *(i32x4*)dst       = *(const i32x4*)vp;
        *(i32x4*)(dst + 8) = *(const i32x4*)(vp + 8);
      } else {
        i32x4 z = {0,0,0,0};
        *(i32x4*)dst = z; *(i32x4*)(dst + 8) = z;
      }
    }
    __syncthreads();
    f32x4 sc[NFV];
    #pragma unroll
    for (int nf=0; nf<NFV; ++nf){
      const US* kb_ = &Ks[(nf*16 + (l&15))*72 + (l>>4)*8];
      f32x4 z = {0.f,0.f,0.f,0.f};
      z = MFMA(aq0, ldsfrag(kb_), z);
      sc[nf] = MFMA(aq1, ldsfrag(kb_ + 32), z);
    }
    #pragma unroll
    for (int nf=0; nf<NFV; ++nf){
      int c = cb + nf*16 + (l&15);
      #pragma unroll
      for (int i=0;i<4;++i){
        int p = prow + i;
        bool valid = LOCAL ? (c >= p - 127 && c <= p) : (c < (p >> lg));
        sc[nf][i] = valid ? sc[nf][i]*0.125f : -1e30f;
      }
    }
    #pragma unroll
    for (int i=0;i<4;++i){
      float tm = sc[0][i];
      #pragma unroll
      for (int nf=1; nf<NFV; ++nf) tm = fmaxf(tm, sc[nf][i]);
      #pragma unroll
      for (int mk=1; mk<16; mk<<=1) tm = fmaxf(tm, __shfl_xor(tm, mk));
      float nm = fmaxf(mrun[i], tm);
      float rsc = __expf(mrun[i] - nm);
      mrun[i] = nm;
      float rs = 0.f;
      #pragma unroll
      for (int nf=0; nf<NFV; ++nf){ float e = __expf(sc[nf][i] - nm); sc[nf][i] = e; rs += e; }
      #pragma unroll
      for (int mk=1; mk<16; mk<<=1) rs += __shfl_xor(rs, mk);
      lsum[i] = lsum[i]*rsc + rs;
      #pragma unroll
      for (int df=0; df<4; ++df) olvl[df][i] *= rsc;
    }
    #pragma unroll
    for (int nf=0; nf<NFV; ++nf)
      #pragma unroll
      for (int i=0;i<4;++i)
        Ps[w*2176 + ((l>>4)*4 + i)*136 + nf*16 + (l&15)] = f2b(sc[nf][i]);
    #pragma unroll
    for (int kf=0; kf<NFV/2; ++kf){
      short8 pa = ldsfrag(&Ps[w*2176 + (l&15)*136 + kf*32 + (l>>4)*8]);
      #pragma unroll
      for (int df=0; df<4; ++df){
        short8 vb_ = ldsfrag(&Vs[(df*16 + (l&15))*136 + kf*32 + (l>>4)*8]);
        olvl[df] = MFMA(pa, vb_, olvl[df]);
      }
    }
  }
}

__global__ __launch_bounds__(512, 4) void attn_fused(
    const US* __restrict__ q, const US* __restrict__ k, const US* __restrict__ vt,
    const US* __restrict__ kc1, const US* __restrict__ vc1t,
    const US* __restrict__ kc2, const US* __restrict__ vc2t,
    const US* __restrict__ kc3, const US* __restrict__ vc3t,
    const float* __restrict__ gamma, US* __restrict__ ao)
{
  __shared__ __attribute__((aligned(16))) US Ks[128*72];
  __shared__ __attribute__((aligned(16))) US Vs[64*136];
  __shared__ __attribute__((aligned(16))) US Ps[8*16*136];
  const int nblk = blockIdx.x, h = blockIdx.y, b = blockIdx.z;
  const int tid = threadIdx.x, l = tid & 63, w = tid >> 6;
  const int bh = b*8 + h;
  const int prow = nblk*128 + w*16 + ((l>>4)<<2);
  short8 aq0, aq1;
  {
    int s = nblk*128 + w*16 + (l & 15);
    const US* qp = q + ((size_t)bh*4096 + s)*64 + (l >> 4)*8;
    aq0 = __builtin_bit_cast(short8, *(const i32x4*)qp);
    aq1 = __builtin_bit_cast(short8, *(const i32x4*)(qp + 32));
  }
  float mrun[4], lsum[4];
  f32x4 olvl[4], oacc[4];
  #pragma unroll
  for (int i=0;i<4;++i) oacc[i] = (f32x4){0.f,0.f,0.f,0.f};

  #pragma unroll
  for (int i=0;i<4;++i){ mrun[i]=-1e30f; lsum[i]=0.f; olvl[i]=(f32x4){0.f,0.f,0.f,0.f}; }
  flash_level<8,true>(k + (size_t)bh*262144, vt + (size_t)bh*262144, 4096, 4096, 4096,
                      (nblk>0)?(nblk-1):0, (nblk>0)?2:1, 0,
                      tid,l,w,prow,aq0,aq1,Ks,Vs,Ps,mrun,lsum,olvl);
  #pragma unroll
  for (int i=0;i<4;++i){
    float wgt = 1.f/lsum[i];
    #pragma unroll
    for (int df=0;df<4;++df) oacc[df][i] += olvl[df][i]*wgt;
  }

  const float g0 = gamma[0], g1 = gamma[1], g2 = gamma[2];

  #pragma unroll
  for (int i=0;i<4;++i){ mrun[i]=-1e30f; lsum[i]=0.f; olvl[i]=(f32x4){0.f,0.f,0.f,0.f}; }
  {
    int cme = (nblk*128 + 127) >> 3;
    int nt = (cme + 127) >> 7;
    flash_level<8,false>(kc1 + (size_t)bh*32768, vc1t + (size_t)bh*32768, 512, 512, 512,
                         0, nt, 3, tid,l,w,prow,aq0,aq1,Ks,Vs,Ps,mrun,lsum,olvl);
  }
  #pragma unroll
  for (int i=0;i<4;++i){
    if (prow + i >= 8){
      float wgt = g0/lsum[i];
      #pragma unroll
      for (int df=0;df<4;++df) oacc[df][i] += olvl[df][i]*wgt;
    }
  }

  #pragma unroll
  for (int i=0;i<4;++i){ mrun[i]=-1e30f; lsum[i]=0.f; olvl[i]=(f32x4){0.f,0.f,0.f,0.f}; }
  flash_level<4,false>(kc2 + (size_t)bh*4096, vc2t + (size_t)bh*4096, 64, 64, 64,
                       0, 1, 6, tid,l,w,prow,aq0,aq1,Ks,Vs,Ps,mrun,lsum,olvl);
  #pragma unroll
  for (int i=0;i<4;++i){
    if (prow + i >= 64){
      float wgt = g1/lsum[i];
      #pragma unroll
      for (int df=0;df<4;++df) oacc[df][i] += olvl[df][i]*wgt;
    }
  }

  if (nblk >= 4){
    #pragma unroll
    for (int i=0;i<4;++i){ mrun[i]=-1e30f; lsum[i]=0.f; olvl[i]=(f32x4){0.f,0.f,0.f,0.f}; }
    flash_level<2,false>(kc3 + (size_t)bh*512, vc3t + (size_t)bh*1024, 16, 8, 16,
                         0, 1, 9, tid,l,w,prow,aq0,aq1,Ks,Vs,Ps,mrun,lsum,olvl);
    #pragma unroll
    for (int i=0;i<4;++i){
      if (prow + i >= 512){
        float wgt = g2/lsum[i];
        #pragma unroll
        for (int df=0;df<4;++df) oacc[df][i] += olvl[df][i]*wgt;
      }
    }
  }

  #pragma unroll
  for (int df=0;df<4;++df)
    #pragma unroll
    for (int i=0;i<4;++i){
      int p = prow + i, d = df*16 + (l&15);
      ao[((size_t)b*4096 + p)*512 + h*64 + d] = f2b(oacc[df][i]);
    }
}

// ---------------- workspace layout ----------------
static constexpr size_t SZ_WT_SQ = (size_t)512*512*2;
static constexpr size_t SZ_WT_FF = (size_t)512*1536*2;
static constexpr size_t SZ_ACT   = (size_t)16384*512*2;
static constexpr size_t O_WQT = 0;
static constexpr size_t O_WKT = O_WQT + SZ_WT_SQ;
static constexpr size_t O_WVT = O_WKT + SZ_WT_SQ;
static constexpr size_t O_WOT = O_WVT + SZ_WT_SQ;
static constexpr size_t O_W1T = O_WOT + SZ_WT_SQ;
static constexpr size_t O_W2T = O_W1T + SZ_WT_FF;
static constexpr size_t O_W3T = O_W2T + SZ_WT_FF;
static constexpr size_t O_XN  = O_W3T + SZ_WT_FF;
static constexpr size_t O_Q   = O_XN + SZ_ACT;
static constexpr size_t O_K   = O_Q + SZ_ACT;
static constexpr size_t O_V   = O_K + SZ_ACT;
static constexpr size_t O_AO  = O_V + SZ_ACT;
static constexpr size_t O_KC1 = O_AO + SZ_ACT;
static constexpr size_t O_VC1T = O_KC1 + (size_t)32*512*64*2;
static constexpr size_t O_KC2  = O_VC1T + (size_t)32*64*512*2;
static constexpr size_t O_VC2T = O_KC2 + (size_t)32*64*64*2;
static constexpr size_t O_KC3  = O_VC2T + (size_t)32*64*64*2;
static constexpr size_t O_VC3T = O_KC3 + (size_t)32*8*64*2;

extern "C" void kernel_launch(void* const* d_in, const int* in_sizes, int n_in,
                              void* d_out, int out_size, void* d_ws, size_t ws_size,
                              hipStream_t stream)
{
  (void)in_sizes; (void)n_in; (void)out_size; (void)ws_size;
  const float* x     = (const float*)d_in[0];
  const float* n1w   = (const float*)d_in[1];
  const float* n2w   = (const float*)d_in[2];
  const float* wq    = (const float*)d_in[3];
  const float* wk    = (const float*)d_in[4];
  const float* wv    = (const float*)d_in[5];
  const float* wo    = (const float*)d_in[6];
  const float* gamma = (const float*)d_in[7];
  const float* w1    = (const float*)d_in[8];
  const float* w2    = (const float*)d_in[9];
  const float* w3    = (const float*)d_in[10];
  float* out = (float*)d_out;
  char* ws = (char*)d_ws;

  US* wqT = (US*)(ws + O_WQT);
  US* wkT = (US*)(ws + O_WKT);
  US* wvT = (US*)(ws + O_WVT);
  US* woT = (US*)(ws + O_WOT);
  US* w1T = (US*)(ws + O_W1T);
  US* w2T = (US*)(ws + O_W2T);
  US* w3T = (US*)(ws + O_W3T);
  US* xn  = (US*)(ws + O_XN);
  US* qb  = (US*)(ws + O_Q);
  US* kb  = (US*)(ws + O_K);
  US* vb  = (US*)(ws + O_V);
  US* ao  = (US*)(ws + O_AO);
  US* kc1 = (US*)(ws + O_KC1);
  US* vc1t = (US*)(ws + O_VC1T);
  US* kc2  = (US*)(ws + O_KC2);
  US* vc2t = (US*)(ws + O_VC2T);
  US* kc3  = (US*)(ws + O_KC3);
  US* vc3t = (US*)(ws + O_VC3T);
  US* vbt = xn;
  US* up1 = (US*)(ws + O_Q);

  WcvtArgs wa;
  wa.src[0]=wq; wa.dst[0]=wqT; wa.R[0]=512;  wa.C[0]=512;
  wa.src[1]=wk; wa.dst[1]=wkT; wa.R[1]=512;  wa.C[1]=512;
  wa.src[2]=wv; wa.dst[2]=wvT; wa.R[2]=512;  wa.C[2]=512;
  wa.src[3]=wo; wa.dst[3]=woT; wa.R[3]=512;  wa.C[3]=512;
  wa.src[4]=w1; wa.dst[4]=w1T; wa.R[4]=512;  wa.C[4]=1536;
  wa.src[5]=w2; wa.dst[5]=w2T; wa.R[5]=512;  wa.C[5]=1536;
  wa.src[6]=w3; wa.dst[6]=w3T; wa.R[6]=1536; wa.C[6]=512;
  wcvt<<<dim3(48,48,7), 256, 0, stream>>>(wa);

  rmsnorm_k<<<dim3(4096), 256, 0, stream>>>(x, n1w, xn);

  // fused QKV, 256^2 pipelined
  gemm256_bt<0><<<dim3(6,64), 512, 0, stream>>>(xn, wqT, 16384,1536,512, (void*)qb, nullptr);

  vtrans<<<dim3(64,32), 256, 0, stream>>>(vb, vbt);

  poolkvt<<<dim3(4096,2), 256, 0, stream>>>(kb,  kc1, vbt,  vc1t, 4096, 512, 9, 512, 9);
  poolkvt<<<dim3(512,2),  256, 0, stream>>>(kc1, kc2, vc1t, vc2t, 512,  64,  6, 64,  6);
  poolkvt<<<dim3(128,2),  256, 0, stream>>>(kc2, kc3, vc2t, vc3t, 64,   8,   3, 16,  4);

  attn_fused<<<dim3(32,8,4), 512, 0, stream>>>(qb, kb, vbt, kc1, vc1t, kc2, vc2t, kc3, vc3t, gamma, ao);

  gemm_bt<1><<<dim3(4,128), 256, 0, stream>>>(ao, woT, 16384,512,512, (void*)out, x, nullptr);

  rmsnorm_k<<<dim3(4096), 256, 0, stream>>>(out, n2w, xn);

  gemm256_bt<2><<<dim3(6,64), 512, 0, stream>>>(xn, w1T, 16384,1536,512, (void*)up1, nullptr);
  gemm256_bt<3><<<dim3(6,64), 512, 0, stream>>>(xn, w2T, 16384,1536,512, (void*)up1, up1);
  gemm_bt<4><<<dim3(4,128), 256, 0, stream>>>(up1, w3T, 16384,512,1536, (void*)out, nullptr, nullptr);
}

// Round 8
// 272.205 us; speedup vs baseline: 1.2333x; 1.2333x over previous
//
#include <hip/hip_runtime.h>
#include <stdint.h>

typedef unsigned short US;
typedef __attribute__((ext_vector_type(8))) short short8;
typedef __attribute__((ext_vector_type(8))) US us8;
typedef __attribute__((ext_vector_type(4))) float f32x4;
typedef __attribute__((ext_vector_type(4))) int i32x4;

#define DEV static __device__ __forceinline__

DEV US f2b(float f){
  uint32_t u = __builtin_bit_cast(uint32_t, f);
  return (US)((u + 0x7fffu + ((u >> 16) & 1u)) >> 16);
}
DEV US f2b_fast(float f){   // round-half-up, 2 ALU ops; used only for P (headroom ok)
  uint32_t u = __builtin_bit_cast(uint32_t, f);
  return (US)((u + 0x8000u) >> 16);
}
DEV float b2f(US s){
  return __builtin_bit_cast(float, (uint32_t)((uint32_t)s << 16));
}
DEV short8 ldsfrag(const US* p){
  return __builtin_bit_cast(short8, *(const i32x4*)p);
}
DEV f32x4 MFMA(short8 a, short8 b, f32x4 c){
  return __builtin_amdgcn_mfma_f32_16x16x32_bf16(a, b, c, 0, 0, 0);
}
DEV void async16(const US* g, US* l){
  __builtin_amdgcn_global_load_lds(
      (const __attribute__((address_space(1))) unsigned int*)(const void*)g,
      (__attribute__((address_space(3))) unsigned int*)(void*)l,
      16, 0, 0);
}

// ---------------- weight transpose + fp32->bf16 cast ----------------
struct WcvtArgs {
  const float* src[7];
  US* dst[7];
  int R[7];
  int C[7];
};

__global__ __launch_bounds__(256) void wcvt(WcvtArgs a){
  int z = blockIdx.z;
  int R = a.R[z], C = a.C[z];
  int tc = blockIdx.x*32, tr = blockIdx.y*32;
  if (tc >= C || tr >= R) return;
  __shared__ float T[32][33];
  int tx = threadIdx.x & 31, ty = threadIdx.x >> 5;
  const float* s = a.src[z];
  #pragma unroll
  for (int j=0;j<4;++j) T[ty + j*8][tx] = s[(size_t)(tr + ty + j*8)*C + tc + tx];
  __syncthreads();
  US* d = a.dst[z];
  #pragma unroll
  for (int j=0;j<4;++j) d[(size_t)(tc + ty + j*8)*R + tr + tx] = f2b(T[tx][ty + j*8]);
}

// ---------------- RMSNorm: fp32 row(512) -> bf16 ----------------
__global__ __launch_bounds__(256) void rmsnorm_k(const float* __restrict__ x,
                                                 const float* __restrict__ w,
                                                 US* __restrict__ o){
  int row = blockIdx.x*4 + (threadIdx.x >> 6);
  int l = threadIdx.x & 63;
  const float* xr = x + (size_t)row*512 + l*8;
  f32x4 a = *(const f32x4*)xr;
  f32x4 b = *(const f32x4*)(xr + 4);
  float ss = a[0]*a[0]+a[1]*a[1]+a[2]*a[2]+a[3]*a[3]
           + b[0]*b[0]+b[1]*b[1]+b[2]*b[2]+b[3]*b[3];
  #pragma unroll
  for (int mk=1; mk<64; mk<<=1) ss += __shfl_xor(ss, mk);
  float r = rsqrtf(ss*(1.0f/512.0f) + 1e-6f);
  const float* wr = w + l*8;
  f32x4 wa = *(const f32x4*)wr;
  f32x4 wb = *(const f32x4*)(wr + 4);
  us8 t;
  t[0]=f2b(a[0]*r*wa[0]); t[1]=f2b(a[1]*r*wa[1]);
  t[2]=f2b(a[2]*r*wa[2]); t[3]=f2b(a[3]*r*wa[3]);
  t[4]=f2b(b[0]*r*wb[0]); t[5]=f2b(b[1]*r*wb[1]);
  t[6]=f2b(b[2]*r*wb[2]); t[7]=f2b(b[3]*r*wb[3]);
  *(us8*)(o + (size_t)row*512 + l*8) = t;
}

// ---------------- GEMM: C[M][N] = A[M][K](bf16) * BT[N][K](bf16) ----------------
// 128x128 tile, BK=64, XOR slot-swizzled LDS, global_load_lds staging.
// EPI: 0=QKV scatter bf16   1=out=auxf+acc   2=bf16 raw   4=out+=acc
template<int EPI>
__global__ __launch_bounds__(256) void gemm_bt(
    const US* __restrict__ A, const US* __restrict__ BT,
    int M, int N, int K,
    void* __restrict__ outp, const float* __restrict__ auxf,
    US* __restrict__ auxb)
{
  __shared__ __attribute__((aligned(16))) US As[128*64];
  __shared__ __attribute__((aligned(16))) US Bs[128*64];
  const int tid = threadIdx.x, l = tid & 63, w = tid >> 6;
  const int wr = w >> 1, wc = w & 1;
  const int gx = gridDim.x;
  int wg = blockIdx.y*gx + blockIdx.x;
  const int nwg = gx * gridDim.y;
  const int qq = nwg >> 3;
  wg = (wg & 7)*qq + (wg >> 3);
  const int m0 = (wg / gx)*128, n0 = (wg % gx)*128;
  (void)M;
  f32x4 acc[4][4] = {};
  for (int k0 = 0; k0 < K; k0 += 64){
    #pragma unroll
    for (int p=0;p<4;++p){
      int off  = p*4096 + w*1024 + l*16;
      int row  = off >> 7;
      int slot = (off >> 4) & 7;
      int ce   = ((slot ^ (row & 7)) << 3);
      async16(A  + (size_t)(m0 + row)*K + k0 + ce, As + p*2048 + w*512);
      async16(BT + (size_t)(n0 + row)*K + k0 + ce, Bs + p*2048 + w*512);
    }
    __syncthreads();
    short8 af[2][4], bg[2][4];
    #pragma unroll
    for (int kk=0;kk<2;++kk){
      const int sA = ((kk*4 + (l>>4)) ^ (l & 7)) << 3;
      #pragma unroll
      for (int i=0;i<4;++i){
        af[kk][i] = ldsfrag(&As[(wr*64 + i*16 + (l&15))*64 + sA]);
        bg[kk][i] = ldsfrag(&Bs[(wc*64 + i*16 + (l&15))*64 + sA]);
      }
    }
    #pragma unroll
    for (int kk=0;kk<2;++kk)
      #pragma unroll
      for (int i=0;i<4;++i)
        #pragma unroll
        for (int j=0;j<4;++j)
          acc[i][j] = MFMA(af[kk][i], bg[kk][j], acc[i][j]);
    __syncthreads();
  }
  #pragma unroll
  for (int i=0;i<4;++i)
    #pragma unroll
    for (int j=0;j<4;++j)
      #pragma unroll
      for (int r=0;r<4;++r){
        int m  = m0 + wr*64 + i*16 + (l>>4)*4 + r;
        int nn = n0 + wc*64 + j*16 + (l&15);
        float val = acc[i][j][r];
        if constexpr (EPI == 0){
          US* o = (US*)outp;
          int f = nn & 511, t = nn >> 9;
          size_t idx = (size_t)t*8388608
                     + ((size_t)(m>>12)*8 + (size_t)(f>>6))*262144
                     + (size_t)(m & 4095)*64 + (size_t)(f & 63);
          o[idx] = f2b(val);
        } else if constexpr (EPI == 1){
          float* o = (float*)outp;
          size_t idx = (size_t)m*N + nn;
          o[idx] = auxf[idx] + val;
        } else if constexpr (EPI == 2){
          US* o = (US*)outp;
          o[(size_t)m*N + nn] = f2b(val);
        } else {
          float* o = (float*)outp;
          size_t idx = (size_t)m*N + nn;
          o[idx] += val;
        }
      }
  (void)auxb;
}

// ---------------- fused FF1+FF2: silu(A@W1T) * (A@W2T) -> bf16 ----------------
__global__ __launch_bounds__(256, 2) void gemm_ff12(
    const US* __restrict__ A, const US* __restrict__ B1T, const US* __restrict__ B2T,
    int N, int K, US* __restrict__ outp)
{
  __shared__ __attribute__((aligned(16))) US As[128*64];
  __shared__ __attribute__((aligned(16))) US B1s[128*64];
  __shared__ __attribute__((aligned(16))) US B2s[128*64];
  const int tid = threadIdx.x, l = tid & 63, w = tid >> 6;
  const int wr = w >> 1, wc = w & 1;
  const int gx = gridDim.x;
  int wg = blockIdx.y*gx + blockIdx.x;
  const int nwg = gx * gridDim.y;
  const int qq = nwg >> 3;
  wg = (wg & 7)*qq + (wg >> 3);
  const int m0 = (wg / gx)*128, n0 = (wg % gx)*128;
  f32x4 acc1[4][4] = {};
  f32x4 acc2[4][4] = {};
  for (int k0 = 0; k0 < K; k0 += 64){
    #pragma unroll
    for (int p=0;p<4;++p){
      int off  = p*4096 + w*1024 + l*16;
      int row  = off >> 7;
      int slot = (off >> 4) & 7;
      int ce   = ((slot ^ (row & 7)) << 3);
      async16(A   + (size_t)(m0 + row)*K + k0 + ce, As  + p*2048 + w*512);
      async16(B1T + (size_t)(n0 + row)*K + k0 + ce, B1s + p*2048 + w*512);
      async16(B2T + (size_t)(n0 + row)*K + k0 + ce, B2s + p*2048 + w*512);
    }
    __syncthreads();
    short8 af[2][4], bg1[2][4], bg2[2][4];
    #pragma unroll
    for (int kk=0;kk<2;++kk){
      const int sA = ((kk*4 + (l>>4)) ^ (l & 7)) << 3;
      #pragma unroll
      for (int i=0;i<4;++i){
        af[kk][i]  = ldsfrag(&As [(wr*64 + i*16 + (l&15))*64 + sA]);
        bg1[kk][i] = ldsfrag(&B1s[(wc*64 + i*16 + (l&15))*64 + sA]);
        bg2[kk][i] = ldsfrag(&B2s[(wc*64 + i*16 + (l&15))*64 + sA]);
      }
    }
    #pragma unroll
    for (int kk=0;kk<2;++kk)
      #pragma unroll
      for (int i=0;i<4;++i)
        #pragma unroll
        for (int j=0;j<4;++j){
          acc1[i][j] = MFMA(af[kk][i], bg1[kk][j], acc1[i][j]);
          acc2[i][j] = MFMA(af[kk][i], bg2[kk][j], acc2[i][j]);
        }
    __syncthreads();
  }
  #pragma unroll
  for (int i=0;i<4;++i)
    #pragma unroll
    for (int j=0;j<4;++j)
      #pragma unroll
      for (int r=0;r<4;++r){
        int m  = m0 + wr*64 + i*16 + (l>>4)*4 + r;
        int nn = n0 + wc*64 + j*16 + (l&15);
        float g = acc1[i][j][r];
        float u = acc2[i][j][r];
        float sg = g / (1.f + __expf(-g));
        outp[(size_t)m*N + nn] = f2b(sg * u);
      }
}

// ---------------- V transpose: [bh][4096][64] -> [bh][64][4096] ----------------
__global__ __launch_bounds__(256) void vtrans(const US* __restrict__ vin,
                                              US* __restrict__ vout){
  __shared__ US T[64*72];
  int s0 = blockIdx.x*64;
  int bh = blockIdx.y;
  int r = threadIdx.x >> 2, c0 = (threadIdx.x & 3)*16;
  const US* src = vin + ((size_t)bh*4096 + s0 + r)*64 + c0;
  *(i32x4*)&T[r*72 + c0]     = *(const i32x4*)src;
  *(i32x4*)&T[r*72 + c0 + 8] = *(const i32x4*)(src + 8);
  __syncthreads();
  int d = threadIdx.x >> 2, e0 = (threadIdx.x & 3)*16;
  US* dst = vout + ((size_t)bh*64 + d)*4096 + s0 + e0;
  us8 o0, o1;
  #pragma unroll
  for (int j=0;j<8;++j){ o0[j] = T[(e0+j)*72 + d]; o1[j] = T[(e0+8+j)*72 + d]; }
  *(us8*)dst = o0;
  *(us8*)(dst + 8) = o1;
}

// ---------------- pooling: K row-major + V^T, one level ----------------
__global__ __launch_bounds__(256) void poolkvt(
    const US* __restrict__ kin, US* __restrict__ kout,
    const US* __restrict__ vtin, US* __restrict__ vtout,
    int nin, int nout, int lgno, int noutS, int lgnoS)
{
  int t = blockIdx.x*256 + threadIdx.x;
  if (blockIdx.y == 0){
    if (t >= (nout << 11)) return;
    int d = t & 63;
    int c = (t >> 6) & (nout - 1);
    int bh = t >> (6 + lgno);
    const US* kp = kin + (((size_t)bh*nin) + (size_t)c*8)*64 + d;
    float s = 0.f;
    #pragma unroll
    for (int j=0;j<8;++j) s += b2f(kp[j*64]);
    kout[((size_t)bh*nout + c)*64 + d] = f2b(s*0.125f);
  } else {
    if (t >= (noutS << 11)) return;
    int c = t & (noutS - 1);
    int row = t >> lgnoS;
    US val = 0;
    if (c < nout){
      const US* vp = vtin + (size_t)row*nin + (size_t)c*8;
      us8 v = *(const us8*)vp;
      float s = 0.f;
      #pragma unroll
      for (int j=0;j<8;++j) s += b2f(v[j]);
      val = f2b(s*0.125f);
    }
    vtout[(size_t)row*noutS + c] = val;
  }
}

// ---------------- fused hierarchical attention (fixed-max softmax) ----------------
// 512 threads = 8 waves x 16 q-rows; scores bounded -> no max-reduce, no rescale.
template<int NFV, bool LOCAL>
DEV void flash_level(const US* __restrict__ kptr, const US* __restrict__ vtp,
                     int vstride, int ncK, int NCV,
                     int tile0, int ntiles, int lg,
                     int tid, int l, int w, int prow,
                     short8 aq0, short8 aq1,
                     US* Ks, US* Vs, US* Ps,
                     float* lsum, f32x4* olvl)
{
  for (int tt=0; tt<ntiles; ++tt){
    const int cb = (tile0 + tt)*128;
    __syncthreads();
    {
      int r = tid >> 2, c0 = (tid & 3)*16;
      if (cb + r < ncK){
        const US* kp = kptr + (size_t)(cb + r)*64 + c0;
        *(i32x4*)&Ks[r*72 + c0]     = *(const i32x4*)kp;
        *(i32x4*)&Ks[r*72 + c0 + 8] = *(const i32x4*)(kp + 8);
      }
      int d = tid >> 3, e0 = (tid & 7)*16;
      US* dst = &Vs[d*136 + e0];
      if (cb + e0 + 16 <= NCV){
        const US* vp = vtp + (size_t)d*vstride + cb + e0;
        *(i32x4*)dst       = *(const i32x4*)vp;
        *(i32x4*)(dst + 8) = *(const i32x4*)(vp + 8);
      } else {
        i32x4 z = {0,0,0,0};
        *(i32x4*)dst = z; *(i32x4*)(dst + 8) = z;
      }
    }
    __syncthreads();
    f32x4 sc[NFV];
    #pragma unroll
    for (int nf=0; nf<NFV; ++nf){
      const US* kb_ = &Ks[(nf*16 + (l&15))*72 + (l>>4)*8];
      f32x4 z = {0.f,0.f,0.f,0.f};
      z = MFMA(aq0, ldsfrag(kb_), z);
      sc[nf] = MFMA(aq1, ldsfrag(kb_ + 32), z);
    }
    #pragma unroll
    for (int nf=0; nf<NFV; ++nf){
      int c = cb + nf*16 + (l&15);
      #pragma unroll
      for (int i=0;i<4;++i){
        int p = prow + i;
        bool valid = LOCAL ? (c >= p - 127 && c <= p) : (c < (p >> lg));
        sc[nf][i] = valid ? sc[nf][i]*0.125f : -1e30f;
      }
    }
    // fixed-max softmax: p = exp(s) (masked -> exp(-1e30) == 0), pure accumulation
    #pragma unroll
    for (int i=0;i<4;++i){
      float rs = 0.f;
      #pragma unroll
      for (int nf=0; nf<NFV; ++nf){ float e = __expf(sc[nf][i]); sc[nf][i] = e; rs += e; }
      #pragma unroll
      for (int mk=1; mk<16; mk<<=1) rs += __shfl_xor(rs, mk);
      lsum[i] += rs;
    }
    #pragma unroll
    for (int nf=0; nf<NFV; ++nf)
      #pragma unroll
      for (int i=0;i<4;++i)
        Ps[w*2176 + ((l>>4)*4 + i)*136 + nf*16 + (l&15)] = f2b_fast(sc[nf][i]);
    #pragma unroll
    for (int kf=0; kf<NFV/2; ++kf){
      short8 pa = ldsfrag(&Ps[w*2176 + (l&15)*136 + kf*32 + (l>>4)*8]);
      #pragma unroll
      for (int df=0; df<4; ++df){
        short8 vb_ = ldsfrag(&Vs[(df*16 + (l&15))*136 + kf*32 + (l>>4)*8]);
        olvl[df] = MFMA(pa, vb_, olvl[df]);
      }
    }
  }
}

__global__ __launch_bounds__(512, 4) void attn_fused(
    const US* __restrict__ q, const US* __restrict__ k, const US* __restrict__ vt,
    const US* __restrict__ kc1, const US* __restrict__ vc1t,
    const US* __restrict__ kc2, const US* __restrict__ vc2t,
    const US* __restrict__ kc3, const US* __restrict__ vc3t,
    const float* __restrict__ gamma, US* __restrict__ ao)
{
  __shared__ __attribute__((aligned(16))) US Ks[128*72];
  __shared__ __attribute__((aligned(16))) US Vs[64*136];
  __shared__ __attribute__((aligned(16))) US Ps[8*16*136];
  const int nblk = blockIdx.x, h = blockIdx.y, b = blockIdx.z;
  const int tid = threadIdx.x, l = tid & 63, w = tid >> 6;
  const int bh = b*8 + h;
  const int prow = nblk*128 + w*16 + ((l>>4)<<2);
  short8 aq0, aq1;
  {
    int s = nblk*128 + w*16 + (l & 15);
    const US* qp = q + ((size_t)bh*4096 + s)*64 + (l >> 4)*8;
    aq0 = __builtin_bit_cast(short8, *(const i32x4*)qp);
    aq1 = __builtin_bit_cast(short8, *(const i32x4*)(qp + 32));
  }
  float lsum[4];
  f32x4 olvl[4], oacc[4];
  #pragma unroll
  for (int i=0;i<4;++i) oacc[i] = (f32x4){0.f,0.f,0.f,0.f};

  // ---- L0: causal local window ----
  #pragma unroll
  for (int i=0;i<4;++i){ lsum[i]=0.f; olvl[i]=(f32x4){0.f,0.f,0.f,0.f}; }
  flash_level<8,true>(k + (size_t)bh*262144, vt + (size_t)bh*262144, 4096, 4096, 4096,
                      (nblk>0)?(nblk-1):0, (nblk>0)?2:1, 0,
                      tid,l,w,prow,aq0,aq1,Ks,Vs,Ps,lsum,olvl);
  #pragma unroll
  for (int i=0;i<4;++i){
    float wgt = 1.f/lsum[i];
    #pragma unroll
    for (int df=0;df<4;++df) oacc[df][i] += olvl[df][i]*wgt;
  }

  const float g0 = gamma[0], g1 = gamma[1], g2 = gamma[2];

  // ---- L1: C=8, nc=512 ----
  #pragma unroll
  for (int i=0;i<4;++i){ lsum[i]=0.f; olvl[i]=(f32x4){0.f,0.f,0.f,0.f}; }
  {
    int cme = (nblk*128 + 127) >> 3;
    int nt = (cme + 127) >> 7;
    flash_level<8,false>(kc1 + (size_t)bh*32768, vc1t + (size_t)bh*32768, 512, 512, 512,
                         0, nt, 3, tid,l,w,prow,aq0,aq1,Ks,Vs,Ps,lsum,olvl);
  }
  #pragma unroll
  for (int i=0;i<4;++i){
    if (prow + i >= 8){
      float wgt = g0/lsum[i];
      #pragma unroll
      for (int df=0;df<4;++df) oacc[df][i] += olvl[df][i]*wgt;
    }
  }

  // ---- L2: C=64, nc=64 ----
  #pragma unroll
  for (int i=0;i<4;++i){ lsum[i]=0.f; olvl[i]=(f32x4){0.f,0.f,0.f,0.f}; }
  flash_level<4,false>(kc2 + (size_t)bh*4096, vc2t + (size_t)bh*4096, 64, 64, 64,
                       0, 1, 6, tid,l,w,prow,aq0,aq1,Ks,Vs,Ps,lsum,olvl);
  #pragma unroll
  for (int i=0;i<4;++i){
    if (prow + i >= 64){
      float wgt = g1/lsum[i];
      #pragma unroll
      for (int df=0;df<4;++df) oacc[df][i] += olvl[df][i]*wgt;
    }
  }

  // ---- L3: C=512, nc=8 ----
  if (nblk >= 4){
    #pragma unroll
    for (int i=0;i<4;++i){ lsum[i]=0.f; olvl[i]=(f32x4){0.f,0.f,0.f,0.f}; }
    flash_level<2,false>(kc3 + (size_t)bh*512, vc3t + (size_t)bh*1024, 16, 8, 16,
                         0, 1, 9, tid,l,w,prow,aq0,aq1,Ks,Vs,Ps,lsum,olvl);
    #pragma unroll
    for (int i=0;i<4;++i){
      if (prow + i >= 512){
        float wgt = g2/lsum[i];
        #pragma unroll
        for (int df=0;df<4;++df) oacc[df][i] += olvl[df][i]*wgt;
      }
    }
  }

  #pragma unroll
  for (int df=0;df<4;++df)
    #pragma unroll
    for (int i=0;i<4;++i){
      int p = prow + i, d = df*16 + (l&15);
      ao[((size_t)b*4096 + p)*512 + h*64 + d] = f2b(oacc[df][i]);
    }
}

// ---------------- workspace layout ----------------
static constexpr size_t SZ_WT_SQ = (size_t)512*512*2;
static constexpr size_t SZ_WT_FF = (size_t)512*1536*2;
static constexpr size_t SZ_ACT   = (size_t)16384*512*2;
static constexpr size_t O_WQT = 0;
static constexpr size_t O_WKT = O_WQT + SZ_WT_SQ;
static constexpr size_t O_WVT = O_WKT + SZ_WT_SQ;
static constexpr size_t O_WOT = O_WVT + SZ_WT_SQ;
static constexpr size_t O_W1T = O_WOT + SZ_WT_SQ;
static constexpr size_t O_W2T = O_W1T + SZ_WT_FF;
static constexpr size_t O_W3T = O_W2T + SZ_WT_FF;
static constexpr size_t O_XN  = O_W3T + SZ_WT_FF;
static constexpr size_t O_Q   = O_XN + SZ_ACT;
static constexpr size_t O_K   = O_Q + SZ_ACT;
static constexpr size_t O_V   = O_K + SZ_ACT;
static constexpr size_t O_AO  = O_V + SZ_ACT;
static constexpr size_t O_KC1 = O_AO + SZ_ACT;
static constexpr size_t O_VC1T = O_KC1 + (size_t)32*512*64*2;
static constexpr size_t O_KC2  = O_VC1T + (size_t)32*64*512*2;
static constexpr size_t O_VC2T = O_KC2 + (size_t)32*64*64*2;
static constexpr size_t O_KC3  = O_VC2T + (size_t)32*64*64*2;
static constexpr size_t O_VC3T = O_KC3 + (size_t)32*8*64*2;

extern "C" void kernel_launch(void* const* d_in, const int* in_sizes, int n_in,
                              void* d_out, int out_size, void* d_ws, size_t ws_size,
                              hipStream_t stream)
{
  (void)in_sizes; (void)n_in; (void)out_size; (void)ws_size;
  const float* x     = (const float*)d_in[0];
  const float* n1w   = (const float*)d_in[1];
  const float* n2w   = (const float*)d_in[2];
  const float* wq    = (const float*)d_in[3];
  const float* wk    = (const float*)d_in[4];
  const float* wv    = (const float*)d_in[5];
  const float* wo    = (const float*)d_in[6];
  const float* gamma = (const float*)d_in[7];
  const float* w1    = (const float*)d_in[8];
  const float* w2    = (const float*)d_in[9];
  const float* w3    = (const float*)d_in[10];
  float* out = (float*)d_out;
  char* ws = (char*)d_ws;

  US* wqT = (US*)(ws + O_WQT);
  US* wkT = (US*)(ws + O_WKT);
  US* wvT = (US*)(ws + O_WVT);
  US* woT = (US*)(ws + O_WOT);
  US* w1T = (US*)(ws + O_W1T);
  US* w2T = (US*)(ws + O_W2T);
  US* w3T = (US*)(ws + O_W3T);
  US* xn  = (US*)(ws + O_XN);
  US* qb  = (US*)(ws + O_Q);
  US* kb  = (US*)(ws + O_K);
  US* vb  = (US*)(ws + O_V);
  US* ao  = (US*)(ws + O_AO);
  US* kc1 = (US*)(ws + O_KC1);
  US* vc1t = (US*)(ws + O_VC1T);
  US* kc2  = (US*)(ws + O_KC2);
  US* vc2t = (US*)(ws + O_VC2T);
  US* kc3  = (US*)(ws + O_KC3);
  US* vc3t = (US*)(ws + O_VC3T);
  US* vbt = xn;
  US* up1 = (US*)(ws + O_Q);

  WcvtArgs wa;
  wa.src[0]=wq; wa.dst[0]=wqT; wa.R[0]=512;  wa.C[0]=512;
  wa.src[1]=wk; wa.dst[1]=wkT; wa.R[1]=512;  wa.C[1]=512;
  wa.src[2]=wv; wa.dst[2]=wvT; wa.R[2]=512;  wa.C[2]=512;
  wa.src[3]=wo; wa.dst[3]=woT; wa.R[3]=512;  wa.C[3]=512;
  wa.src[4]=w1; wa.dst[4]=w1T; wa.R[4]=512;  wa.C[4]=1536;
  wa.src[5]=w2; wa.dst[5]=w2T; wa.R[5]=512;  wa.C[5]=1536;
  wa.src[6]=w3; wa.dst[6]=w3T; wa.R[6]=1536; wa.C[6]=512;
  wcvt<<<dim3(48,48,7), 256, 0, stream>>>(wa);

  rmsnorm_k<<<dim3(4096), 256, 0, stream>>>(x, n1w, xn);

  gemm_bt<0><<<dim3(12,128), 256, 0, stream>>>(xn, wqT, 16384,1536,512, (void*)qb, nullptr, nullptr);

  vtrans<<<dim3(64,32), 256, 0, stream>>>(vb, vbt);

  poolkvt<<<dim3(4096,2), 256, 0, stream>>>(kb,  kc1, vbt,  vc1t, 4096, 512, 9, 512, 9);
  poolkvt<<<dim3(512,2),  256, 0, stream>>>(kc1, kc2, vc1t, vc2t, 512,  64,  6, 64,  6);
  poolkvt<<<dim3(128,2),  256, 0, stream>>>(kc2, kc3, vc2t, vc3t, 64,   8,   3, 16,  4);

  attn_fused<<<dim3(32,8,4), 512, 0, stream>>>(qb, kb, vbt, kc1, vc1t, kc2, vc2t, kc3, vc3t, gamma, ao);

  gemm_bt<1><<<dim3(4,128), 256, 0, stream>>>(ao, woT, 16384,512,512, (void*)out, x, nullptr);

  rmsnorm_k<<<dim3(4096), 256, 0, stream>>>(out, n2w, xn);

  gemm_ff12<<<dim3(12,128), 256, 0, stream>>>(xn, w1T, w2T, 1536, 512, up1);

  gemm_bt<4><<<dim3(4,128), 256, 0, stream>>>(up1, w3T, 16384,512,1536, (void*)out, nullptr, nullptr);
}

// Round 9
// 269.657 us; speedup vs baseline: 1.2450x; 1.0094x over previous
//
#include <hip/hip_runtime.h>
#include <stdint.h>

typedef unsigned short US;
typedef __attribute__((ext_vector_type(8))) short short8;
typedef __attribute__((ext_vector_type(8))) US us8;
typedef __attribute__((ext_vector_type(4))) float f32x4;
typedef __attribute__((ext_vector_type(4))) int i32x4;

#define DEV static __device__ __forceinline__

DEV US f2b(float f){
  uint32_t u = __builtin_bit_cast(uint32_t, f);
  return (US)((u + 0x7fffu + ((u >> 16) & 1u)) >> 16);
}
DEV US f2b_fast(float f){
  uint32_t u = __builtin_bit_cast(uint32_t, f);
  return (US)((u + 0x8000u) >> 16);
}
DEV float b2f(US s){
  return __builtin_bit_cast(float, (uint32_t)((uint32_t)s << 16));
}
DEV short8 ldsfrag(const US* p){
  return __builtin_bit_cast(short8, *(const i32x4*)p);
}
DEV f32x4 MFMA(short8 a, short8 b, f32x4 c){
  return __builtin_amdgcn_mfma_f32_16x16x32_bf16(a, b, c, 0, 0, 0);
}
DEV void async16(const US* g, US* l){
  __builtin_amdgcn_global_load_lds(
      (const __attribute__((address_space(1))) unsigned int*)(const void*)g,
      (__attribute__((address_space(3))) unsigned int*)(void*)l,
      16, 0, 0);
}

// ---------------- weight transpose + fp32->bf16 cast ----------------
struct WcvtArgs {
  const float* src[7];
  US* dst[7];
  int R[7];
  int C[7];
};

__global__ __launch_bounds__(256) void wcvt(WcvtArgs a){
  int z = blockIdx.z;
  int R = a.R[z], C = a.C[z];
  int tc = blockIdx.x*32, tr = blockIdx.y*32;
  if (tc >= C || tr >= R) return;
  __shared__ float T[32][33];
  int tx = threadIdx.x & 31, ty = threadIdx.x >> 5;
  const float* s = a.src[z];
  #pragma unroll
  for (int j=0;j<4;++j) T[ty + j*8][tx] = s[(size_t)(tr + ty + j*8)*C + tc + tx];
  __syncthreads();
  US* d = a.dst[z];
  #pragma unroll
  for (int j=0;j<4;++j) d[(size_t)(tc + ty + j*8)*R + tr + tx] = f2b(T[tx][ty + j*8]);
}

// ---------------- RMSNorm: fp32 row(512) -> bf16 ----------------
__global__ __launch_bounds__(256) void rmsnorm_k(const float* __restrict__ x,
                                                 const float* __restrict__ w,
                                                 US* __restrict__ o){
  int row = blockIdx.x*4 + (threadIdx.x >> 6);
  int l = threadIdx.x & 63;
  const float* xr = x + (size_t)row*512 + l*8;
  f32x4 a = *(const f32x4*)xr;
  f32x4 b = *(const f32x4*)(xr + 4);
  float ss = a[0]*a[0]+a[1]*a[1]+a[2]*a[2]+a[3]*a[3]
           + b[0]*b[0]+b[1]*b[1]+b[2]*b[2]+b[3]*b[3];
  #pragma unroll
  for (int mk=1; mk<64; mk<<=1) ss += __shfl_xor(ss, mk);
  float r = rsqrtf(ss*(1.0f/512.0f) + 1e-6f);
  const float* wr = w + l*8;
  f32x4 wa = *(const f32x4*)wr;
  f32x4 wb = *(const f32x4*)(wr + 4);
  us8 t;
  t[0]=f2b(a[0]*r*wa[0]); t[1]=f2b(a[1]*r*wa[1]);
  t[2]=f2b(a[2]*r*wa[2]); t[3]=f2b(a[3]*r*wa[3]);
  t[4]=f2b(b[0]*r*wb[0]); t[5]=f2b(b[1]*r*wb[1]);
  t[6]=f2b(b[2]*r*wb[2]); t[7]=f2b(b[3]*r*wb[3]);
  *(us8*)(o + (size_t)row*512 + l*8) = t;
}

// ---------------- GEMM: C[M][N] = A[M][K](bf16) * BT[N][K](bf16) ----------------
// 128x128 tile, BK=64, XOR slot-swizzled LDS, global_load_lds staging.
template<int EPI>
__global__ __launch_bounds__(256) void gemm_bt(
    const US* __restrict__ A, const US* __restrict__ BT,
    int M, int N, int K,
    void* __restrict__ outp, const float* __restrict__ auxf,
    US* __restrict__ auxb)
{
  __shared__ __attribute__((aligned(16))) US As[128*64];
  __shared__ __attribute__((aligned(16))) US Bs[128*64];
  const int tid = threadIdx.x, l = tid & 63, w = tid >> 6;
  const int wr = w >> 1, wc = w & 1;
  const int gx = gridDim.x;
  int wg = blockIdx.y*gx + blockIdx.x;
  const int nwg = gx * gridDim.y;
  const int qq = nwg >> 3;
  wg = (wg & 7)*qq + (wg >> 3);
  const int m0 = (wg / gx)*128, n0 = (wg % gx)*128;
  (void)M;
  f32x4 acc[4][4] = {};
  for (int k0 = 0; k0 < K; k0 += 64){
    #pragma unroll
    for (int p=0;p<4;++p){
      int off  = p*4096 + w*1024 + l*16;
      int row  = off >> 7;
      int slot = (off >> 4) & 7;
      int ce   = ((slot ^ (row & 7)) << 3);
      async16(A  + (size_t)(m0 + row)*K + k0 + ce, As + p*2048 + w*512);
      async16(BT + (size_t)(n0 + row)*K + k0 + ce, Bs + p*2048 + w*512);
    }
    __syncthreads();
    short8 af[2][4], bg[2][4];
    #pragma unroll
    for (int kk=0;kk<2;++kk){
      const int sA = ((kk*4 + (l>>4)) ^ (l & 7)) << 3;
      #pragma unroll
      for (int i=0;i<4;++i){
        af[kk][i] = ldsfrag(&As[(wr*64 + i*16 + (l&15))*64 + sA]);
        bg[kk][i] = ldsfrag(&Bs[(wc*64 + i*16 + (l&15))*64 + sA]);
      }
    }
    #pragma unroll
    for (int kk=0;kk<2;++kk)
      #pragma unroll
      for (int i=0;i<4;++i)
        #pragma unroll
        for (int j=0;j<4;++j)
          acc[i][j] = MFMA(af[kk][i], bg[kk][j], acc[i][j]);
    __syncthreads();
  }
  #pragma unroll
  for (int i=0;i<4;++i)
    #pragma unroll
    for (int j=0;j<4;++j)
      #pragma unroll
      for (int r=0;r<4;++r){
        int m  = m0 + wr*64 + i*16 + (l>>4)*4 + r;
        int nn = n0 + wc*64 + j*16 + (l&15);
        float val = acc[i][j][r];
        if constexpr (EPI == 0){
          US* o = (US*)outp;
          int f = nn & 511, t = nn >> 9;
          size_t idx = (size_t)t*8388608
                     + ((size_t)(m>>12)*8 + (size_t)(f>>6))*262144
                     + (size_t)(m & 4095)*64 + (size_t)(f & 63);
          o[idx] = f2b(val);
        } else if constexpr (EPI == 1){
          float* o = (float*)outp;
          size_t idx = (size_t)m*N + nn;
          o[idx] = auxf[idx] + val;
        } else if constexpr (EPI == 2){
          US* o = (US*)outp;
          o[(size_t)m*N + nn] = f2b(val);
        } else {
          float* o = (float*)outp;
          size_t idx = (size_t)m*N + nn;
          o[idx] += val;
        }
      }
  (void)auxb;
}

// ---------------- fused FF1+FF2: silu(A@W1T) * (A@W2T) -> bf16 ----------------
// 512 threads, 2M x 4N wave grid, per-wave 64x32 dual-acc (64 VGPR) -> 16 waves/CU.
__global__ __launch_bounds__(512) void gemm_ff12(
    const US* __restrict__ A, const US* __restrict__ B1T, const US* __restrict__ B2T,
    int N, int K, US* __restrict__ outp)
{
  __shared__ __attribute__((aligned(16))) US As[128*64];
  __shared__ __attribute__((aligned(16))) US B1s[128*64];
  __shared__ __attribute__((aligned(16))) US B2s[128*64];
  const int tid = threadIdx.x, l = tid & 63, w = tid >> 6;
  const int wr = w >> 2, wc = w & 3;
  const int gx = gridDim.x;
  int wg = blockIdx.y*gx + blockIdx.x;
  const int nwg = gx * gridDim.y;
  const int qq = nwg >> 3;
  wg = (wg & 7)*qq + (wg >> 3);
  const int m0 = (wg / gx)*128, n0 = (wg % gx)*128;
  f32x4 acc1[4][2] = {};
  f32x4 acc2[4][2] = {};
  for (int k0 = 0; k0 < K; k0 += 64){
    #pragma unroll
    for (int p=0;p<2;++p){
      int off  = p*8192 + tid*16;
      int row  = off >> 7;
      int slot = (off >> 4) & 7;
      int ce   = ((slot ^ (row & 7)) << 3);
      async16(A   + (size_t)(m0 + row)*K + k0 + ce, As  + p*4096 + w*512);
      async16(B1T + (size_t)(n0 + row)*K + k0 + ce, B1s + p*4096 + w*512);
      async16(B2T + (size_t)(n0 + row)*K + k0 + ce, B2s + p*4096 + w*512);
    }
    __syncthreads();
    #pragma unroll
    for (int kk=0;kk<2;++kk){
      short8 af[4], b1[2], b2[2];
      #pragma unroll
      for (int i=0;i<4;++i){
        int row = wr*64 + i*16 + (l&15);
        int s = ((kk*4 + (l>>4)) ^ (row & 7)) << 3;
        af[i] = ldsfrag(&As[row*64 + s]);
      }
      #pragma unroll
      for (int j=0;j<2;++j){
        int row = wc*32 + j*16 + (l&15);
        int s = ((kk*4 + (l>>4)) ^ (row & 7)) << 3;
        b1[j] = ldsfrag(&B1s[row*64 + s]);
        b2[j] = ldsfrag(&B2s[row*64 + s]);
      }
      #pragma unroll
      for (int i=0;i<4;++i)
        #pragma unroll
        for (int j=0;j<2;++j){
          acc1[i][j] = MFMA(af[i], b1[j], acc1[i][j]);
          acc2[i][j] = MFMA(af[i], b2[j], acc2[i][j]);
        }
    }
    __syncthreads();
  }
  #pragma unroll
  for (int i=0;i<4;++i)
    #pragma unroll
    for (int j=0;j<2;++j)
      #pragma unroll
      for (int r=0;r<4;++r){
        int m  = m0 + wr*64 + i*16 + (l>>4)*4 + r;
        int nn = n0 + wc*32 + j*16 + (l&15);
        float g = acc1[i][j][r];
        float u = acc2[i][j][r];
        float sg = g / (1.f + __expf(-g));
        outp[(size_t)m*N + nn] = f2b(sg * u);
      }
}

// ---------------- V transpose: [bh][4096][64] -> [bh][64][4096] ----------------
__global__ __launch_bounds__(256) void vtrans(const US* __restrict__ vin,
                                              US* __restrict__ vout){
  __shared__ US T[64*72];
  int s0 = blockIdx.x*64;
  int bh = blockIdx.y;
  int r = threadIdx.x >> 2, c0 = (threadIdx.x & 3)*16;
  const US* src = vin + ((size_t)bh*4096 + s0 + r)*64 + c0;
  *(i32x4*)&T[r*72 + c0]     = *(const i32x4*)src;
  *(i32x4*)&T[r*72 + c0 + 8] = *(const i32x4*)(src + 8);
  __syncthreads();
  int d = threadIdx.x >> 2, e0 = (threadIdx.x & 3)*16;
  US* dst = vout + ((size_t)bh*64 + d)*4096 + s0 + e0;
  us8 o0, o1;
  #pragma unroll
  for (int j=0;j<8;++j){ o0[j] = T[(e0+j)*72 + d]; o1[j] = T[(e0+8+j)*72 + d]; }
  *(us8*)dst = o0;
  *(us8*)(dst + 8) = o1;
}

// ---------------- pooling: K row-major + V^T, one level ----------------
__global__ __launch_bounds__(256) void poolkvt(
    const US* __restrict__ kin, US* __restrict__ kout,
    const US* __restrict__ vtin, US* __restrict__ vtout,
    int nin, int nout, int lgno, int noutS, int lgnoS)
{
  int t = blockIdx.x*256 + threadIdx.x;
  if (blockIdx.y == 0){
    if (t >= (nout << 11)) return;
    int d = t & 63;
    int c = (t >> 6) & (nout - 1);
    int bh = t >> (6 + lgno);
    const US* kp = kin + (((size_t)bh*nin) + (size_t)c*8)*64 + d;
    float s = 0.f;
    #pragma unroll
    for (int j=0;j<8;++j) s += b2f(kp[j*64]);
    kout[((size_t)bh*nout + c)*64 + d] = f2b(s*0.125f);
  } else {
    if (t >= (noutS << 11)) return;
    int c = t & (noutS - 1);
    int row = t >> lgnoS;
    US val = 0;
    if (c < nout){
      const US* vp = vtin + (size_t)row*nin + (size_t)c*8;
      us8 v = *(const us8*)vp;
      float s = 0.f;
      #pragma unroll
      for (int j=0;j<8;++j) s += b2f(v[j]);
      val = f2b(s*0.125f);
    }
    vtout[(size_t)row*noutS + c] = val;
  }
}

// ---------------- fused hierarchical attention ----------------
// K/V staged via global_load_lds into XOR-swizzled linear LDS (Ks[128][64], Vs[64][128]).
// Unstaged rows/cols are only read where the mask forces P=0 (stale data is finite).
template<int NFV, bool LOCAL>
DEV void flash_level(const US* __restrict__ kptr, const US* __restrict__ vtp,
                     int vstride, int ncK, int NCV,
                     int tile0, int ntiles, int lg,
                     int tid, int l, int w, int prow,
                     short8 aq0, short8 aq1,
                     US* Ks, US* Vs, US* Ps,
                     float* lsum, f32x4* olvl)
{
  for (int tt=0; tt<ntiles; ++tt){
    const int cb = (tile0 + tt)*128;
    __syncthreads();   // prior tile's PV done -> safe to restage
    #pragma unroll
    for (int is=0; is<2; ++is){
      int off  = is*8192 + tid*16;
      {
        int row  = off >> 7;
        int slot = (off >> 4) & 7;
        int ce   = ((slot ^ (row & 7)) << 3);
        if (cb + row < ncK)
          async16(kptr + (size_t)(cb + row)*64 + ce, Ks + is*4096 + w*512);
      }
      {
        int row = off >> 8;
        int q   = ((off >> 4) & 15) ^ (row & 7);
        if (cb + q*8 < NCV)
          async16(vtp + (size_t)row*vstride + cb + q*8, Vs + is*4096 + w*512);
      }
    }
    __syncthreads();
    f32x4 sc[NFV];
    #pragma unroll
    for (int nf=0; nf<NFV; ++nf){
      int row = nf*16 + (l&15);
      const US* base = &Ks[row*64];
      int s0 = (((l>>4)    ) ^ (row & 7)) << 3;
      int s1 = (((l>>4) + 4) ^ (row & 7)) << 3;
      f32x4 z = {0.f,0.f,0.f,0.f};
      z = MFMA(aq0, ldsfrag(base + s0), z);
      sc[nf] = MFMA(aq1, ldsfrag(base + s1), z);
    }
    #pragma unroll
    for (int nf=0; nf<NFV; ++nf){
      int c = cb + nf*16 + (l&15);
      #pragma unroll
      for (int i=0;i<4;++i){
        int p = prow + i;
        bool valid = LOCAL ? (c >= p - 127 && c <= p) : (c < (p >> lg));
        sc[nf][i] = valid ? sc[nf][i]*0.125f : -1e30f;
      }
    }
    // fixed-max softmax: p = exp(s), masked -> 0
    #pragma unroll
    for (int i=0;i<4;++i){
      float rs = 0.f;
      #pragma unroll
      for (int nf=0; nf<NFV; ++nf){ float e = __expf(sc[nf][i]); sc[nf][i] = e; rs += e; }
      #pragma unroll
      for (int mk=1; mk<16; mk<<=1) rs += __shfl_xor(rs, mk);
      lsum[i] += rs;
    }
    #pragma unroll
    for (int nf=0; nf<NFV; ++nf)
      #pragma unroll
      for (int i=0;i<4;++i)
        Ps[w*2176 + ((l>>4)*4 + i)*136 + nf*16 + (l&15)] = f2b_fast(sc[nf][i]);
    #pragma unroll
    for (int kf=0; kf<NFV/2; ++kf){
      short8 pa = ldsfrag(&Ps[w*2176 + (l&15)*136 + kf*32 + (l>>4)*8]);
      #pragma unroll
      for (int df=0; df<4; ++df){
        int row = df*16 + (l&15);
        int s = ((kf*4 + (l>>4)) ^ (row & 7)) << 3;
        short8 vb_ = ldsfrag(&Vs[row*128 + s]);
        olvl[df] = MFMA(pa, vb_, olvl[df]);
      }
    }
  }
}

__global__ __launch_bounds__(512, 4) void attn_fused(
    const US* __restrict__ q, const US* __restrict__ k, const US* __restrict__ vt,
    const US* __restrict__ kc1, const US* __restrict__ vc1t,
    const US* __restrict__ kc2, const US* __restrict__ vc2t,
    const US* __restrict__ kc3, const US* __restrict__ vc3t,
    const float* __restrict__ gamma, US* __restrict__ ao)
{
  __shared__ __attribute__((aligned(16))) US Ks[128*64];
  __shared__ __attribute__((aligned(16))) US Vs[64*128];
  __shared__ __attribute__((aligned(16))) US Ps[8*16*136];
  const int nblk = blockIdx.x, h = blockIdx.y, b = blockIdx.z;
  const int tid = threadIdx.x, l = tid & 63, w = tid >> 6;
  const int bh = b*8 + h;
  const int prow = nblk*128 + w*16 + ((l>>4)<<2);
  short8 aq0, aq1;
  {
    int s = nblk*128 + w*16 + (l & 15);
    const US* qp = q + ((size_t)bh*4096 + s)*64 + (l >> 4)*8;
    aq0 = __builtin_bit_cast(short8, *(const i32x4*)qp);
    aq1 = __builtin_bit_cast(short8, *(const i32x4*)(qp + 32));
  }
  float lsum[4];
  f32x4 olvl[4], oacc[4];
  #pragma unroll
  for (int i=0;i<4;++i) oacc[i] = (f32x4){0.f,0.f,0.f,0.f};

  // ---- L0: causal local window ----
  #pragma unroll
  for (int i=0;i<4;++i){ lsum[i]=0.f; olvl[i]=(f32x4){0.f,0.f,0.f,0.f}; }
  flash_level<8,true>(k + (size_t)bh*262144, vt + (size_t)bh*262144, 4096, 4096, 4096,
                      (nblk>0)?(nblk-1):0, (nblk>0)?2:1, 0,
                      tid,l,w,prow,aq0,aq1,Ks,Vs,Ps,lsum,olvl);
  #pragma unroll
  for (int i=0;i<4;++i){
    float wgt = 1.f/lsum[i];
    #pragma unroll
    for (int df=0;df<4;++df) oacc[df][i] += olvl[df][i]*wgt;
  }

  const float g0 = gamma[0], g1 = gamma[1], g2 = gamma[2];

  // ---- L1: C=8, nc=512 ----
  #pragma unroll
  for (int i=0;i<4;++i){ lsum[i]=0.f; olvl[i]=(f32x4){0.f,0.f,0.f,0.f}; }
  {
    int cme = (nblk*128 + 127) >> 3;
    int nt = (cme + 127) >> 7;
    flash_level<8,false>(kc1 + (size_t)bh*32768, vc1t + (size_t)bh*32768, 512, 512, 512,
                         0, nt, 3, tid,l,w,prow,aq0,aq1,Ks,Vs,Ps,lsum,olvl);
  }
  #pragma unroll
  for (int i=0;i<4;++i){
    if (prow + i >= 8){
      float wgt = g0/lsum[i];
      #pragma unroll
      for (int df=0;df<4;++df) oacc[df][i] += olvl[df][i]*wgt;
    }
  }

  // ---- L2: C=64, nc=64 ----
  #pragma unroll
  for (int i=0;i<4;++i){ lsum[i]=0.f; olvl[i]=(f32x4){0.f,0.f,0.f,0.f}; }
  flash_level<4,false>(kc2 + (size_t)bh*4096, vc2t + (size_t)bh*4096, 64, 64, 64,
                       0, 1, 6, tid,l,w,prow,aq0,aq1,Ks,Vs,Ps,lsum,olvl);
  #pragma unroll
  for (int i=0;i<4;++i){
    if (prow + i >= 64){
      float wgt = g1/lsum[i];
      #pragma unroll
      for (int df=0;df<4;++df) oacc[df][i] += olvl[df][i]*wgt;
    }
  }

  // ---- L3: C=512, nc=8 ----
  if (nblk >= 4){
    #pragma unroll
    for (int i=0;i<4;++i){ lsum[i]=0.f; olvl[i]=(f32x4){0.f,0.f,0.f,0.f}; }
    flash_level<2,false>(kc3 + (size_t)bh*512, vc3t + (size_t)bh*1024, 16, 8, 16,
                         0, 1, 9, tid,l,w,prow,aq0,aq1,Ks,Vs,Ps,lsum,olvl);
    #pragma unroll
    for (int i=0;i<4;++i){
      if (prow + i >= 512){
        float wgt = g2/lsum[i];
        #pragma unroll
        for (int df=0;df<4;++df) oacc[df][i] += olvl[df][i]*wgt;
      }
    }
  }

  #pragma unroll
  for (int df=0;df<4;++df)
    #pragma unroll
    for (int i=0;i<4;++i){
      int p = prow + i, d = df*16 + (l&15);
      ao[((size_t)b*4096 + p)*512 + h*64 + d] = f2b(oacc[df][i]);
    }
}

// ---------------- workspace layout ----------------
static constexpr size_t SZ_WT_SQ = (size_t)512*512*2;
static constexpr size_t SZ_WT_FF = (size_t)512*1536*2;
static constexpr size_t SZ_ACT   = (size_t)16384*512*2;
static constexpr size_t O_WQT = 0;
static constexpr size_t O_WKT = O_WQT + SZ_WT_SQ;
static constexpr size_t O_WVT = O_WKT + SZ_WT_SQ;
static constexpr size_t O_WOT = O_WVT + SZ_WT_SQ;
static constexpr size_t O_W1T = O_WOT + SZ_WT_SQ;
static constexpr size_t O_W2T = O_W1T + SZ_WT_FF;
static constexpr size_t O_W3T = O_W2T + SZ_WT_FF;
static constexpr size_t O_XN  = O_W3T + SZ_WT_FF;
static constexpr size_t O_Q   = O_XN + SZ_ACT;
static constexpr size_t O_K   = O_Q + SZ_ACT;
static constexpr size_t O_V   = O_K + SZ_ACT;
static constexpr size_t O_AO  = O_V + SZ_ACT;
static constexpr size_t O_KC1 = O_AO + SZ_ACT;
static constexpr size_t O_VC1T = O_KC1 + (size_t)32*512*64*2;
static constexpr size_t O_KC2  = O_VC1T + (size_t)32*64*512*2;
static constexpr size_t O_VC2T = O_KC2 + (size_t)32*64*64*2;
static constexpr size_t O_KC3  = O_VC2T + (size_t)32*64*64*2;
static constexpr size_t O_VC3T = O_KC3 + (size_t)32*8*64*2;

extern "C" void kernel_launch(void* const* d_in, const int* in_sizes, int n_in,
                              void* d_out, int out_size, void* d_ws, size_t ws_size,
                              hipStream_t stream)
{
  (void)in_sizes; (void)n_in; (void)out_size; (void)ws_size;
  const float* x     = (const float*)d_in[0];
  const float* n1w   = (const float*)d_in[1];
  const float* n2w   = (const float*)d_in[2];
  const float* wq    = (const float*)d_in[3];
  const float* wk    = (const float*)d_in[4];
  const float* wv    = (const float*)d_in[5];
  const float* wo    = (const float*)d_in[6];
  const float* gamma = (const float*)d_in[7];
  const float* w1    = (const float*)d_in[8];
  const float* w2    = (const float*)d_in[9];
  const float* w3    = (const float*)d_in[10];
  float* out = (float*)d_out;
  char* ws = (char*)d_ws;

  US* wqT = (US*)(ws + O_WQT);
  US* wkT = (US*)(ws + O_WKT);
  US* wvT = (US*)(ws + O_WVT);
  US* woT = (US*)(ws + O_WOT);
  US* w1T = (US*)(ws + O_W1T);
  US* w2T = (US*)(ws + O_W2T);
  US* w3T = (US*)(ws + O_W3T);
  US* xn  = (US*)(ws + O_XN);
  US* qb  = (US*)(ws + O_Q);
  US* kb  = (US*)(ws + O_K);
  US* vb  = (US*)(ws + O_V);
  US* ao  = (US*)(ws + O_AO);
  US* kc1 = (US*)(ws + O_KC1);
  US* vc1t = (US*)(ws + O_VC1T);
  US* kc2  = (US*)(ws + O_KC2);
  US* vc2t = (US*)(ws + O_VC2T);
  US* kc3  = (US*)(ws + O_KC3);
  US* vc3t = (US*)(ws + O_VC3T);
  US* vbt = xn;
  US* up1 = (US*)(ws + O_Q);

  WcvtArgs wa;
  wa.src[0]=wq; wa.dst[0]=wqT; wa.R[0]=512;  wa.C[0]=512;
  wa.src[1]=wk; wa.dst[1]=wkT; wa.R[1]=512;  wa.C[1]=512;
  wa.src[2]=wv; wa.dst[2]=wvT; wa.R[2]=512;  wa.C[2]=512;
  wa.src[3]=wo; wa.dst[3]=woT; wa.R[3]=512;  wa.C[3]=512;
  wa.src[4]=w1; wa.dst[4]=w1T; wa.R[4]=512;  wa.C[4]=1536;
  wa.src[5]=w2; wa.dst[5]=w2T; wa.R[5]=512;  wa.C[5]=1536;
  wa.src[6]=w3; wa.dst[6]=w3T; wa.R[6]=1536; wa.C[6]=512;
  wcvt<<<dim3(48,48,7), 256, 0, stream>>>(wa);

  rmsnorm_k<<<dim3(4096), 256, 0, stream>>>(x, n1w, xn);

  gemm_bt<0><<<dim3(12,128), 256, 0, stream>>>(xn, wqT, 16384,1536,512, (void*)qb, nullptr, nullptr);

  vtrans<<<dim3(64,32), 256, 0, stream>>>(vb, vbt);

  poolkvt<<<dim3(4096,2), 256, 0, stream>>>(kb,  kc1, vbt,  vc1t, 4096, 512, 9, 512, 9);
  poolkvt<<<dim3(512,2),  256, 0, stream>>>(kc1, kc2, vc1t, vc2t, 512,  64,  6, 64,  6);
  poolkvt<<<dim3(128,2),  256, 0, stream>>>(kc2, kc3, vc2t, vc3t, 64,   8,   3, 16,  4);

  attn_fused<<<dim3(32,8,4), 512, 0, stream>>>(qb, kb, vbt, kc1, vc1t, kc2, vc2t, kc3, vc3t, gamma, ao);

  gemm_bt<1><<<dim3(4,128), 256, 0, stream>>>(ao, woT, 16384,512,512, (void*)out, x, nullptr);

  rmsnorm_k<<<dim3(4096), 256, 0, stream>>>(out, n2w, xn);

  gemm_ff12<<<dim3(12,128), 512, 0, stream>>>(xn, w1T, w2T, 1536, 512, up1);

  gemm_bt<4><<<dim3(4,128), 256, 0, stream>>>(up1, w3T, 16384,512,1536, (void*)out, nullptr, nullptr);
}

// Round 10
// 259.223 us; speedup vs baseline: 1.2951x; 1.0403x over previous
//
#include <hip/hip_runtime.h>
#include <stdint.h>

typedef unsigned short US;
typedef __attribute__((ext_vector_type(8))) short short8;
typedef __attribute__((ext_vector_type(8))) US us8;
typedef __attribute__((ext_vector_type(4))) float f32x4;
typedef __attribute__((ext_vector_type(4))) int i32x4;

#define DEV static __device__ __forceinline__

DEV US f2b(float f){
  uint32_t u = __builtin_bit_cast(uint32_t, f);
  return (US)((u + 0x7fffu + ((u >> 16) & 1u)) >> 16);
}
DEV US f2b_fast(float f){
  uint32_t u = __builtin_bit_cast(uint32_t, f);
  return (US)((u + 0x8000u) >> 16);
}
DEV float b2f(US s){
  return __builtin_bit_cast(float, (uint32_t)((uint32_t)s << 16));
}
DEV short8 ldsfrag(const US* p){
  return __builtin_bit_cast(short8, *(const i32x4*)p);
}
DEV f32x4 MFMA(short8 a, short8 b, f32x4 c){
  return __builtin_amdgcn_mfma_f32_16x16x32_bf16(a, b, c, 0, 0, 0);
}
DEV void async16(const US* g, US* l){
  __builtin_amdgcn_global_load_lds(
      (const __attribute__((address_space(1))) unsigned int*)(const void*)g,
      (__attribute__((address_space(3))) unsigned int*)(void*)l,
      16, 0, 0);
}

// ---------------- weight transpose + fp32->bf16 cast ----------------
struct WcvtArgs {
  const float* src[7];
  US* dst[7];
  int R[7];
  int C[7];
};

__global__ __launch_bounds__(256) void wcvt(WcvtArgs a){
  int z = blockIdx.z;
  int R = a.R[z], C = a.C[z];
  int tc = blockIdx.x*32, tr = blockIdx.y*32;
  if (tc >= C || tr >= R) return;
  __shared__ float T[32][33];
  int tx = threadIdx.x & 31, ty = threadIdx.x >> 5;
  const float* s = a.src[z];
  #pragma unroll
  for (int j=0;j<4;++j) T[ty + j*8][tx] = s[(size_t)(tr + ty + j*8)*C + tc + tx];
  __syncthreads();
  US* d = a.dst[z];
  #pragma unroll
  for (int j=0;j<4;++j) d[(size_t)(tc + ty + j*8)*R + tr + tx] = f2b(T[tx][ty + j*8]);
}

// ---------------- RMSNorm: fp32 row(512) -> bf16 ----------------
__global__ __launch_bounds__(256) void rmsnorm_k(const float* __restrict__ x,
                                                 const float* __restrict__ w,
                                                 US* __restrict__ o){
  int row = blockIdx.x*4 + (threadIdx.x >> 6);
  int l = threadIdx.x & 63;
  const float* xr = x + (size_t)row*512 + l*8;
  f32x4 a = *(const f32x4*)xr;
  f32x4 b = *(const f32x4*)(xr + 4);
  float ss = a[0]*a[0]+a[1]*a[1]+a[2]*a[2]+a[3]*a[3]
           + b[0]*b[0]+b[1]*b[1]+b[2]*b[2]+b[3]*b[3];
  #pragma unroll
  for (int mk=1; mk<64; mk<<=1) ss += __shfl_xor(ss, mk);
  float r = rsqrtf(ss*(1.0f/512.0f) + 1e-6f);
  const float* wr = w + l*8;
  f32x4 wa = *(const f32x4*)wr;
  f32x4 wb = *(const f32x4*)(wr + 4);
  us8 t;
  t[0]=f2b(a[0]*r*wa[0]); t[1]=f2b(a[1]*r*wa[1]);
  t[2]=f2b(a[2]*r*wa[2]); t[3]=f2b(a[3]*r*wa[3]);
  t[4]=f2b(b[0]*r*wb[0]); t[5]=f2b(b[1]*r*wb[1]);
  t[6]=f2b(b[2]*r*wb[2]); t[7]=f2b(b[3]*r*wb[3]);
  *(us8*)(o + (size_t)row*512 + l*8) = t;
}

// ---------------- GEMM: C[M][N] = A[M][K](bf16) * BT[N][K](bf16) ----------------
// 128x128 tile, BK=64, XOR slot-swizzled LDS, global_load_lds staging.
// EPI 0 additionally scales the q-third (nn<512) by 0.125 (attn score scale folded in).
template<int EPI>
__global__ __launch_bounds__(256) void gemm_bt(
    const US* __restrict__ A, const US* __restrict__ BT,
    int M, int N, int K,
    void* __restrict__ outp, const float* __restrict__ auxf,
    US* __restrict__ auxb)
{
  __shared__ __attribute__((aligned(16))) US As[128*64];
  __shared__ __attribute__((aligned(16))) US Bs[128*64];
  const int tid = threadIdx.x, l = tid & 63, w = tid >> 6;
  const int wr = w >> 1, wc = w & 1;
  const int gx = gridDim.x;
  int wg = blockIdx.y*gx + blockIdx.x;
  const int nwg = gx * gridDim.y;
  const int qq = nwg >> 3;
  wg = (wg & 7)*qq + (wg >> 3);
  const int m0 = (wg / gx)*128, n0 = (wg % gx)*128;
  (void)M;
  f32x4 acc[4][4] = {};
  for (int k0 = 0; k0 < K; k0 += 64){
    #pragma unroll
    for (int p=0;p<4;++p){
      int off  = p*4096 + w*1024 + l*16;
      int row  = off >> 7;
      int slot = (off >> 4) & 7;
      int ce   = ((slot ^ (row & 7)) << 3);
      async16(A  + (size_t)(m0 + row)*K + k0 + ce, As + p*2048 + w*512);
      async16(BT + (size_t)(n0 + row)*K + k0 + ce, Bs + p*2048 + w*512);
    }
    __syncthreads();
    short8 af[2][4], bg[2][4];
    #pragma unroll
    for (int kk=0;kk<2;++kk){
      const int sA = ((kk*4 + (l>>4)) ^ (l & 7)) << 3;
      #pragma unroll
      for (int i=0;i<4;++i){
        af[kk][i] = ldsfrag(&As[(wr*64 + i*16 + (l&15))*64 + sA]);
        bg[kk][i] = ldsfrag(&Bs[(wc*64 + i*16 + (l&15))*64 + sA]);
      }
    }
    #pragma unroll
    for (int kk=0;kk<2;++kk)
      #pragma unroll
      for (int i=0;i<4;++i)
        #pragma unroll
        for (int j=0;j<4;++j)
          acc[i][j] = MFMA(af[kk][i], bg[kk][j], acc[i][j]);
    __syncthreads();
  }
  #pragma unroll
  for (int i=0;i<4;++i)
    #pragma unroll
    for (int j=0;j<4;++j)
      #pragma unroll
      for (int r=0;r<4;++r){
        int m  = m0 + wr*64 + i*16 + (l>>4)*4 + r;
        int nn = n0 + wc*64 + j*16 + (l&15);
        float val = acc[i][j][r];
        if constexpr (EPI == 0){
          US* o = (US*)outp;
          if (nn < 512) val *= 0.125f;   // fold attn score scale into Q
          int f = nn & 511, t = nn >> 9;
          size_t idx = (size_t)t*8388608
                     + ((size_t)(m>>12)*8 + (size_t)(f>>6))*262144
                     + (size_t)(m & 4095)*64 + (size_t)(f & 63);
          o[idx] = f2b(val);
        } else if constexpr (EPI == 1){
          float* o = (float*)outp;
          size_t idx = (size_t)m*N + nn;
          o[idx] = auxf[idx] + val;
        } else if constexpr (EPI == 2){
          US* o = (US*)outp;
          o[(size_t)m*N + nn] = f2b(val);
        } else {
          float* o = (float*)outp;
          size_t idx = (size_t)m*N + nn;
          o[idx] += val;
        }
      }
  (void)auxb;
}

// ---------------- fused FF1+FF2: silu(A@W1T) * (A@W2T) -> bf16 ----------------
__global__ __launch_bounds__(512) void gemm_ff12(
    const US* __restrict__ A, const US* __restrict__ B1T, const US* __restrict__ B2T,
    int N, int K, US* __restrict__ outp)
{
  __shared__ __attribute__((aligned(16))) US As[128*64];
  __shared__ __attribute__((aligned(16))) US B1s[128*64];
  __shared__ __attribute__((aligned(16))) US B2s[128*64];
  const int tid = threadIdx.x, l = tid & 63, w = tid >> 6;
  const int wr = w >> 2, wc = w & 3;
  const int gx = gridDim.x;
  int wg = blockIdx.y*gx + blockIdx.x;
  const int nwg = gx * gridDim.y;
  const int qq = nwg >> 3;
  wg = (wg & 7)*qq + (wg >> 3);
  const int m0 = (wg / gx)*128, n0 = (wg % gx)*128;
  f32x4 acc1[4][2] = {};
  f32x4 acc2[4][2] = {};
  for (int k0 = 0; k0 < K; k0 += 64){
    #pragma unroll
    for (int p=0;p<2;++p){
      int off  = p*8192 + tid*16;
      int row  = off >> 7;
      int slot = (off >> 4) & 7;
      int ce   = ((slot ^ (row & 7)) << 3);
      async16(A   + (size_t)(m0 + row)*K + k0 + ce, As  + p*4096 + w*512);
      async16(B1T + (size_t)(n0 + row)*K + k0 + ce, B1s + p*4096 + w*512);
      async16(B2T + (size_t)(n0 + row)*K + k0 + ce, B2s + p*4096 + w*512);
    }
    __syncthreads();
    #pragma unroll
    for (int kk=0;kk<2;++kk){
      short8 af[4], b1[2], b2[2];
      #pragma unroll
      for (int i=0;i<4;++i){
        int row = wr*64 + i*16 + (l&15);
        int s = ((kk*4 + (l>>4)) ^ (row & 7)) << 3;
        af[i] = ldsfrag(&As[row*64 + s]);
      }
      #pragma unroll
      for (int j=0;j<2;++j){
        int row = wc*32 + j*16 + (l&15);
        int s = ((kk*4 + (l>>4)) ^ (row & 7)) << 3;
        b1[j] = ldsfrag(&B1s[row*64 + s]);
        b2[j] = ldsfrag(&B2s[row*64 + s]);
      }
      #pragma unroll
      for (int i=0;i<4;++i)
        #pragma unroll
        for (int j=0;j<2;++j){
          acc1[i][j] = MFMA(af[i], b1[j], acc1[i][j]);
          acc2[i][j] = MFMA(af[i], b2[j], acc2[i][j]);
        }
    }
    __syncthreads();
  }
  #pragma unroll
  for (int i=0;i<4;++i)
    #pragma unroll
    for (int j=0;j<2;++j)
      #pragma unroll
      for (int r=0;r<4;++r){
        int m  = m0 + wr*64 + i*16 + (l>>4)*4 + r;
        int nn = n0 + wc*32 + j*16 + (l&15);
        float g = acc1[i][j][r];
        float u = acc2[i][j][r];
        float sg = g / (1.f + __expf(-g));
        outp[(size_t)m*N + nn] = f2b(sg * u);
      }
}

// ---------------- V transpose: [bh][4096][64] -> [bh][64][4096] ----------------
__global__ __launch_bounds__(256) void vtrans(const US* __restrict__ vin,
                                              US* __restrict__ vout){
  __shared__ US T[64*72];
  int s0 = blockIdx.x*64;
  int bh = blockIdx.y;
  int r = threadIdx.x >> 2, c0 = (threadIdx.x & 3)*16;
  const US* src = vin + ((size_t)bh*4096 + s0 + r)*64 + c0;
  *(i32x4*)&T[r*72 + c0]     = *(const i32x4*)src;
  *(i32x4*)&T[r*72 + c0 + 8] = *(const i32x4*)(src + 8);
  __syncthreads();
  int d = threadIdx.x >> 2, e0 = (threadIdx.x & 3)*16;
  US* dst = vout + ((size_t)bh*64 + d)*4096 + s0 + e0;
  us8 o0, o1;
  #pragma unroll
  for (int j=0;j<8;++j){ o0[j] = T[(e0+j)*72 + d]; o1[j] = T[(e0+8+j)*72 + d]; }
  *(us8*)dst = o0;
  *(us8*)(dst + 8) = o1;
}

// ---------------- pooling: K row-major + V^T, one level ----------------
__global__ __launch_bounds__(256) void poolkvt(
    const US* __restrict__ kin, US* __restrict__ kout,
    const US* __restrict__ vtin, US* __restrict__ vtout,
    int nin, int nout, int lgno, int noutS, int lgnoS)
{
  int t = blockIdx.x*256 + threadIdx.x;
  if (blockIdx.y == 0){
    if (t >= (nout << 11)) return;
    int d = t & 63;
    int c = (t >> 6) & (nout - 1);
    int bh = t >> (6 + lgno);
    const US* kp = kin + (((size_t)bh*nin) + (size_t)c*8)*64 + d;
    float s = 0.f;
    #pragma unroll
    for (int j=0;j<8;++j) s += b2f(kp[j*64]);
    kout[((size_t)bh*nout + c)*64 + d] = f2b(s*0.125f);
  } else {
    if (t >= (noutS << 11)) return;
    int c = t & (noutS - 1);
    int row = t >> lgnoS;
    US val = 0;
    if (c < nout){
      const US* vp = vtin + (size_t)row*nin + (size_t)c*8;
      us8 v = *(const us8*)vp;
      float s = 0.f;
      #pragma unroll
      for (int j=0;j<8;++j) s += b2f(v[j]);
      val = f2b(s*0.125f);
    }
    vtout[(size_t)row*noutS + c] = val;
  }
}

// ---------------- fused hierarchical attention ----------------
// K/V staged via global_load_lds into XOR-swizzled linear LDS.
// Fixed-max softmax (bounded scores); scale pre-folded into Q.
template<int NFV, bool LOCAL>
DEV void flash_level(const US* __restrict__ kptr, const US* __restrict__ vtp,
                     int vstride, int ncK, int NCV,
                     int tile0, int ntiles, int lg,
                     int tid, int l, int w, int prow,
                     short8 aq0, short8 aq1,
                     US* Ks, US* Vs, US* Ps,
                     float* lsum, f32x4* olvl)
{
  for (int tt=0; tt<ntiles; ++tt){
    const int cb = (tile0 + tt)*128;
    __syncthreads();
    #pragma unroll
    for (int is=0; is<2; ++is){
      int off  = is*8192 + tid*16;
      {
        int row  = off >> 7;
        int slot = (off >> 4) & 7;
        int ce   = ((slot ^ (row & 7)) << 3);
        if (cb + row < ncK)
          async16(kptr + (size_t)(cb + row)*64 + ce, Ks + is*4096 + w*512);
      }
      {
        int row = off >> 8;
        int q   = ((off >> 4) & 15) ^ (row & 7);
        if (cb + q*8 < NCV)
          async16(vtp + (size_t)row*vstride + cb + q*8, Vs + is*4096 + w*512);
      }
    }
    __syncthreads();
    f32x4 sc[NFV];
    #pragma unroll
    for (int nf=0; nf<NFV; ++nf){
      int row = nf*16 + (l&15);
      const US* base = &Ks[row*64];
      int s0 = (((l>>4)    ) ^ (row & 7)) << 3;
      int s1 = (((l>>4) + 4) ^ (row & 7)) << 3;
      f32x4 z = {0.f,0.f,0.f,0.f};
      z = MFMA(aq0, ldsfrag(base + s0), z);
      sc[nf] = MFMA(aq1, ldsfrag(base + s1), z);
    }
    #pragma unroll
    for (int nf=0; nf<NFV; ++nf){
      int c = cb + nf*16 + (l&15);
      #pragma unroll
      for (int i=0;i<4;++i){
        int p = prow + i;
        bool valid = LOCAL ? (c >= p - 127 && c <= p) : (c < (p >> lg));
        sc[nf][i] = valid ? sc[nf][i] : -1e30f;
      }
    }
    #pragma unroll
    for (int i=0;i<4;++i){
      float rs = 0.f;
      #pragma unroll
      for (int nf=0; nf<NFV; ++nf){ float e = __expf(sc[nf][i]); sc[nf][i] = e; rs += e; }
      #pragma unroll
      for (int mk=1; mk<16; mk<<=1) rs += __shfl_xor(rs, mk);
      lsum[i] += rs;
    }
    #pragma unroll
    for (int nf=0; nf<NFV; ++nf)
      #pragma unroll
      for (int i=0;i<4;++i)
        Ps[w*2176 + ((l>>4)*4 + i)*136 + nf*16 + (l&15)] = f2b_fast(sc[nf][i]);
    #pragma unroll
    for (int kf=0; kf<NFV/2; ++kf){
      short8 pa = ldsfrag(&Ps[w*2176 + (l&15)*136 + kf*32 + (l>>4)*8]);
      #pragma unroll
      for (int df=0; df<4; ++df){
        int row = df*16 + (l&15);
        int s = ((kf*4 + (l>>4)) ^ (row & 7)) << 3;
        short8 vb_ = ldsfrag(&Vs[row*128 + s]);
        olvl[df] = MFMA(pa, vb_, olvl[df]);
      }
    }
  }
}

__global__ __launch_bounds__(512, 4) void attn_fused(
    const US* __restrict__ q, const US* __restrict__ k, const US* __restrict__ vt,
    const US* __restrict__ kc1, const US* __restrict__ vc1t,
    const US* __restrict__ kc2, const US* __restrict__ vc2t,
    const US* __restrict__ kc3, const US* __restrict__ vc3t,
    const float* __restrict__ gamma, US* __restrict__ ao)
{
  __shared__ __attribute__((aligned(16))) US Ks[128*64];
  __shared__ __attribute__((aligned(16))) US Vs[64*128];
  __shared__ __attribute__((aligned(16))) US Ps[8*16*136];
  // XCD-pinned mapping: bh ≡ xcd (mod 8) so each XCD's L2 serves 4 (b,h) KV sets;
  // heavy blocks (large nblk) dispatch first within each stream.
  const int fid = blockIdx.x + 32*(blockIdx.y + 8*blockIdx.z);
  const int bh   = (fid & 7) + 8*(fid >> 8);
  const int nblk = 31 - ((fid >> 3) & 31);
  const int b = bh >> 3, h = bh & 7;
  const int tid = threadIdx.x, l = tid & 63, w = tid >> 6;
  const int prow = nblk*128 + w*16 + ((l>>4)<<2);
  short8 aq0, aq1;
  {
    int s = nblk*128 + w*16 + (l & 15);
    const US* qp = q + ((size_t)bh*4096 + s)*64 + (l >> 4)*8;
    aq0 = __builtin_bit_cast(short8, *(const i32x4*)qp);
    aq1 = __builtin_bit_cast(short8, *(const i32x4*)(qp + 32));
  }
  float lsum[4];
  f32x4 olvl[4], oacc[4];
  #pragma unroll
  for (int i=0;i<4;++i) oacc[i] = (f32x4){0.f,0.f,0.f,0.f};

  // ---- L0: causal local window ----
  #pragma unroll
  for (int i=0;i<4;++i){ lsum[i]=0.f; olvl[i]=(f32x4){0.f,0.f,0.f,0.f}; }
  flash_level<8,true>(k + (size_t)bh*262144, vt + (size_t)bh*262144, 4096, 4096, 4096,
                      (nblk>0)?(nblk-1):0, (nblk>0)?2:1, 0,
                      tid,l,w,prow,aq0,aq1,Ks,Vs,Ps,lsum,olvl);
  #pragma unroll
  for (int i=0;i<4;++i){
    float wgt = 1.f/lsum[i];
    #pragma unroll
    for (int df=0;df<4;++df) oacc[df][i] += olvl[df][i]*wgt;
  }

  const float g0 = gamma[0], g1 = gamma[1], g2 = gamma[2];

  // ---- L1: C=8, nc=512 ----
  #pragma unroll
  for (int i=0;i<4;++i){ lsum[i]=0.f; olvl[i]=(f32x4){0.f,0.f,0.f,0.f}; }
  {
    int cme = (nblk*128 + 127) >> 3;
    int nt = (cme + 127) >> 7;
    flash_level<8,false>(kc1 + (size_t)bh*32768, vc1t + (size_t)bh*32768, 512, 512, 512,
                         0, nt, 3, tid,l,w,prow,aq0,aq1,Ks,Vs,Ps,lsum,olvl);
  }
  #pragma unroll
  for (int i=0;i<4;++i){
    if (prow + i >= 8){
      float wgt = g0/lsum[i];
      #pragma unroll
      for (int df=0;df<4;++df) oacc[df][i] += olvl[df][i]*wgt;
    }
  }

  // ---- L2: C=64, nc=64 ----
  #pragma unroll
  for (int i=0;i<4;++i){ lsum[i]=0.f; olvl[i]=(f32x4){0.f,0.f,0.f,0.f}; }
  flash_level<4,false>(kc2 + (size_t)bh*4096, vc2t + (size_t)bh*4096, 64, 64, 64,
                       0, 1, 6, tid,l,w,prow,aq0,aq1,Ks,Vs,Ps,lsum,olvl);
  #pragma unroll
  for (int i=0;i<4;++i){
    if (prow + i >= 64){
      float wgt = g1/lsum[i];
      #pragma unroll
      for (int df=0;df<4;++df) oacc[df][i] += olvl[df][i]*wgt;
    }
  }

  // ---- L3: C=512, nc=8 ----
  if (nblk >= 4){
    #pragma unroll
    for (int i=0;i<4;++i){ lsum[i]=0.f; olvl[i]=(f32x4){0.f,0.f,0.f,0.f}; }
    flash_level<2,false>(kc3 + (size_t)bh*512, vc3t + (size_t)bh*1024, 16, 8, 16,
                         0, 1, 9, tid,l,w,prow,aq0,aq1,Ks,Vs,Ps,lsum,olvl);
    #pragma unroll
    for (int i=0;i<4;++i){
      if (prow + i >= 512){
        float wgt = g2/lsum[i];
        #pragma unroll
        for (int df=0;df<4;++df) oacc[df][i] += olvl[df][i]*wgt;
      }
    }
  }

  #pragma unroll
  for (int df=0;df<4;++df)
    #pragma unroll
    for (int i=0;i<4;++i){
      int p = prow + i, d = df*16 + (l&15);
      ao[((size_t)b*4096 + p)*512 + h*64 + d] = f2b(oacc[df][i]);
    }
}

// ---------------- workspace layout ----------------
static constexpr size_t SZ_WT_SQ = (size_t)512*512*2;
static constexpr size_t SZ_WT_FF = (size_t)512*1536*2;
static constexpr size_t SZ_ACT   = (size_t)16384*512*2;
static constexpr size_t O_WQT = 0;
static constexpr size_t O_WKT = O_WQT + SZ_WT_SQ;
static constexpr size_t O_WVT = O_WKT + SZ_WT_SQ;
static constexpr size_t O_WOT = O_WVT + SZ_WT_SQ;
static constexpr size_t O_W1T = O_WOT + SZ_WT_SQ;
static constexpr size_t O_W2T = O_W1T + SZ_WT_FF;
static constexpr size_t O_W3T = O_W2T + SZ_WT_FF;
static constexpr size_t O_XN  = O_W3T + SZ_WT_FF;
static constexpr size_t O_Q   = O_XN + SZ_ACT;
static constexpr size_t O_K   = O_Q + SZ_ACT;
static constexpr size_t O_V   = O_K + SZ_ACT;
static constexpr size_t O_AO  = O_V + SZ_ACT;
static constexpr size_t O_KC1 = O_AO + SZ_ACT;
static constexpr size_t O_VC1T = O_KC1 + (size_t)32*512*64*2;
static constexpr size_t O_KC2  = O_VC1T + (size_t)32*64*512*2;
static constexpr size_t O_VC2T = O_KC2 + (size_t)32*64*64*2;
static constexpr size_t O_KC3  = O_VC2T + (size_t)32*64*64*2;
static constexpr size_t O_VC3T = O_KC3 + (size_t)32*8*64*2;

extern "C" void kernel_launch(void* const* d_in, const int* in_sizes, int n_in,
                              void* d_out, int out_size, void* d_ws, size_t ws_size,
                              hipStream_t stream)
{
  (void)in_sizes; (void)n_in; (void)out_size; (void)ws_size;
  const float* x     = (const float*)d_in[0];
  const float* n1w   = (const float*)d_in[1];
  const float* n2w   = (const float*)d_in[2];
  const float* wq    = (const float*)d_in[3];
  const float* wk    = (const float*)d_in[4];
  const float* wv    = (const float*)d_in[5];
  const float* wo    = (const float*)d_in[6];
  const float* gamma = (const float*)d_in[7];
  const float* w1    = (const float*)d_in[8];
  const float* w2    = (const float*)d_in[9];
  const float* w3    = (const float*)d_in[10];
  float* out = (float*)d_out;
  char* ws = (char*)d_ws;

  US* wqT = (US*)(ws + O_WQT);
  US* wkT = (US*)(ws + O_WKT);
  US* wvT = (US*)(ws + O_WVT);
  US* woT = (US*)(ws + O_WOT);
  US* w1T = (US*)(ws + O_W1T);
  US* w2T = (US*)(ws + O_W2T);
  US* w3T = (US*)(ws + O_W3T);
  US* xn  = (US*)(ws + O_XN);
  US* qb  = (US*)(ws + O_Q);
  US* kb  = (US*)(ws + O_K);
  US* vb  = (US*)(ws + O_V);
  US* ao  = (US*)(ws + O_AO);
  US* kc1 = (US*)(ws + O_KC1);
  US* vc1t = (US*)(ws + O_VC1T);
  US* kc2  = (US*)(ws + O_KC2);
  US* vc2t = (US*)(ws + O_VC2T);
  US* kc3  = (US*)(ws + O_KC3);
  US* vc3t = (US*)(ws + O_VC3T);
  US* vbt = xn;
  US* up1 = (US*)(ws + O_Q);

  WcvtArgs wa;
  wa.src[0]=wq; wa.dst[0]=wqT; wa.R[0]=512;  wa.C[0]=512;
  wa.src[1]=wk; wa.dst[1]=wkT; wa.R[1]=512;  wa.C[1]=512;
  wa.src[2]=wv; wa.dst[2]=wvT; wa.R[2]=512;  wa.C[2]=512;
  wa.src[3]=wo; wa.dst[3]=woT; wa.R[3]=512;  wa.C[3]=512;
  wa.src[4]=w1; wa.dst[4]=w1T; wa.R[4]=512;  wa.C[4]=1536;
  wa.src[5]=w2; wa.dst[5]=w2T; wa.R[5]=512;  wa.C[5]=1536;
  wa.src[6]=w3; wa.dst[6]=w3T; wa.R[6]=1536; wa.C[6]=512;
  wcvt<<<dim3(48,48,7), 256, 0, stream>>>(wa);

  rmsnorm_k<<<dim3(4096), 256, 0, stream>>>(x, n1w, xn);

  gemm_bt<0><<<dim3(12,128), 256, 0, stream>>>(xn, wqT, 16384,1536,512, (void*)qb, nullptr, nullptr);

  vtrans<<<dim3(64,32), 256, 0, stream>>>(vb, vbt);

  poolkvt<<<dim3(4096,2), 256, 0, stream>>>(kb,  kc1, vbt,  vc1t, 4096, 512, 9, 512, 9);
  poolkvt<<<dim3(512,2),  256, 0, stream>>>(kc1, kc2, vc1t, vc2t, 512,  64,  6, 64,  6);
  poolkvt<<<dim3(128,2),  256, 0, stream>>>(kc2, kc3, vc2t, vc3t, 64,   8,   3, 16,  4);

  attn_fused<<<dim3(32,8,4), 512, 0, stream>>>(qb, kb, vbt, kc1, vc1t, kc2, vc2t, kc3, vc3t, gamma, ao);

  gemm_bt<1><<<dim3(4,128), 256, 0, stream>>>(ao, woT, 16384,512,512, (void*)out, x, nullptr);

  rmsnorm_k<<<dim3(4096), 256, 0, stream>>>(out, n2w, xn);

  gemm_ff12<<<dim3(12,128), 512, 0, stream>>>(xn, w1T, w2T, 1536, 512, up1);

  gemm_bt<4><<<dim3(4,128), 256, 0, stream>>>(up1, w3T, 16384,512,1536, (void*)out, nullptr, nullptr);
}